// Round 4
// baseline (4002.620 us; speedup 1.0000x reference)
//
#include <hip/hip_runtime.h>
#include <hip/hip_cooperative_groups.h>
#include <math.h>

namespace cg = cooperative_groups;

#define T_LEN 32512
#define NTILES 508
#define NPAIR 254
#define BATCH 2
#define NMEL 80
#define FRAMES 128
#define NBLK 30

typedef short bfrag __attribute__((ext_vector_type(8)));
typedef float facc __attribute__((ext_vector_type(4)));
typedef ushort us4v __attribute__((ext_vector_type(4)));
typedef ushort us8v __attribute__((ext_vector_type(8)));

#define MFMA16(a, b, c) __builtin_amdgcn_mfma_f32_16x16x32_bf16((a), (b), (c), 0, 0, 0)

// ---- workspace layout (byte offsets) ----
#define RES0_OFF   0u          // fp32 [2][64][T]  16,646,144
#define RES1_OFF   16646144u   // fp32 [2][64][T]
#define COND_OFF   33292288u   // bf16 [2][80][T]  10,403,840
#define WA_OFF     43696128u   // bf16 30*56*512
#define WSF_OFF    45416448u   // bf16 30*16*512
#define WRF_OFF    45907968u   // bf16 30*8*512
#define WP1_OFF    46153728u   // bf16 64*512
#define WP2_OFF    46219264u   // bf16 128*512
#define CONDA_OFF  46350336u   // bf16 256*25*512
#define ZB_OFF     52903936u   // f32 30*128
#define SBS_OFF    52919296u   // f32 128
#define SKIPG_OFF  52919808u   // f32 [2][128][T] (fallback only) 33,292,288
#define Y1R_OFF    0u          // bf16 [2][256][T] aliases RES0+RES1 (dead after loop)
// total ~86.2 MB

static __device__ __forceinline__ ushort f2bf(float f) {
  union { float f; unsigned int u; } v;
  v.f = f;
  unsigned int r = (v.u + 0x7FFFu + ((v.u >> 16) & 1u)) >> 16;
  return (ushort)r;
}
static __device__ __forceinline__ float sigmoidf_(float x) {
  return 1.f / (1.f + __expf(-x));
}
static __device__ __forceinline__ float tanhf_(float x) {
  return 2.f / (1.f + __expf(-2.f * x)) - 1.f;
}
static __device__ __forceinline__ bfrag ldfrag(const ushort* p) {
  return *reinterpret_cast<const bfrag*>(p);
}

// ---- prep: all weights into MFMA A-fragment bf16 + condA + bias precomps ----
__global__ __launch_bounds__(256) void prep_kernel(
    const float* __restrict__ dil_w, const float* __restrict__ cond_w,
    const float* __restrict__ skip_w, const float* __restrict__ res_w,
    const float* __restrict__ p1_w, const float* __restrict__ p2_w,
    const float* __restrict__ mel_w, const float* __restrict__ dil_b,
    const float* __restrict__ cond_b, const float* __restrict__ skip_b,
    ushort* __restrict__ wa, ushort* __restrict__ wsf, ushort* __restrict__ wrf,
    ushort* __restrict__ wp1, ushort* __restrict__ wp2,
    ushort* __restrict__ condA, float* __restrict__ zb,
    float* __restrict__ sbs) {
  int tid = blockIdx.x * blockDim.x + threadIdx.x;
  int stride = gridDim.x * blockDim.x;
  // W_all[layer][128 m][224 k]: k<64 dil tap0; k<128 dil tap1; k<208 cond; else 0
  for (int idx = tid; idx < NBLK * 56 * 512; idx += stride) {
    int j = idx & 7, lane = (idx >> 3) & 63;
    int f = (idx >> 9) % 56, layer = idx / (56 * 512);
    int mt = f / 7, kt = f % 7;
    int m = 16 * mt + (lane & 15);
    int k = 32 * kt + 8 * (lane >> 4) + j;
    float v;
    if (k < 64)       v = dil_w[(((size_t)layer * 128 + m) * 64 + k) * 2 + 0];
    else if (k < 128) v = dil_w[(((size_t)layer * 128 + m) * 64 + (k - 64)) * 2 + 1];
    else if (k < 208) v = cond_w[((size_t)layer * 128 + m) * 80 + (k - 128)];
    else              v = 0.f;
    wa[idx] = f2bf(v);
  }
  for (int idx = tid; idx < NBLK * 16 * 512; idx += stride) {
    int j = idx & 7, lane = (idx >> 3) & 63;
    int f = (idx >> 9) & 15, layer = idx / (16 * 512);
    int mt = f >> 1, kt = f & 1;
    int m = 16 * mt + (lane & 15);
    int k = 32 * kt + 8 * (lane >> 4) + j;
    wsf[idx] = f2bf(skip_w[((size_t)layer * 128 + m) * 64 + k]);
  }
  for (int idx = tid; idx < NBLK * 8 * 512; idx += stride) {
    int j = idx & 7, lane = (idx >> 3) & 63;
    int f = (idx >> 9) & 7, layer = idx / (8 * 512);
    int mt = f >> 1, kt = f & 1;
    int m = 16 * mt + (lane & 15);
    int k = 32 * kt + 8 * (lane >> 4) + j;
    wrf[idx] = f2bf(res_w[((size_t)layer * 64 + m) * 64 + k]);
  }
  for (int idx = tid; idx < 64 * 512; idx += stride) {
    int j = idx & 7, lane = (idx >> 3) & 63;
    int f = idx >> 9;
    int mt = f >> 2, kt = f & 3;
    int m = 16 * mt + (lane & 15);
    int k = 32 * kt + 8 * (lane >> 4) + j;
    wp1[idx] = f2bf(p1_w[(size_t)m * 128 + k]);
  }
  for (int idx = tid; idx < 128 * 512; idx += stride) {
    int j = idx & 7, lane = (idx >> 3) & 63;
    int f = idx >> 9;
    int mt = f >> 3, kt = f & 7;
    int m = 16 * mt + (lane & 15);
    int k = 32 * kt + 8 * (lane >> 4) + j;
    wp2[idx] = f2bf(p2_w[(size_t)m * 256 + k]);
  }
  // condA[u][f=mt*5+kt][512]: A_u[m=c(80)][k(160)]
  for (int idx = tid; idx < 25 * 512 * 256; idx += stride) {
    int u = idx & 255;
    int e = idx >> 8;
    int j = e & 7, lane = (e >> 3) & 63, f = e >> 9;
    int mt = f / 5, kt = f % 5;
    int m = 16 * mt + (lane & 15);
    int k = 32 * kt + 8 * (lane >> 4) + j;
    int ci = (k < 80) ? k : k - 80;
    int kk = (k < 80) ? (255 - u) : (511 - u);
    condA[((size_t)u * 25 + f) * 512 + lane * 8 + j] =
        f2bf(mel_w[((size_t)m * 80 + ci) * 512 + kk]);
  }
  for (int idx = tid; idx < NBLK * 128; idx += stride)
    zb[idx] = dil_b[idx] + cond_b[idx];
  for (int idx = tid; idx < 128; idx += stride) {
    float s = 0.f;
    for (int i2 = 0; i2 < NBLK; ++i2) s += skip_b[i2 * 128 + idx];
    sbs[idx] = s;
  }
}

// ---- mel upsample as MFMA GEMM per u ----
#define BSTR 168
__global__ __launch_bounds__(256) void cond_mfma(
    const float* __restrict__ mels, const ushort* __restrict__ condA,
    const float* __restrict__ mel_b, ushort* __restrict__ cond) {
  __shared__ ushort BT[128 * BSTR];
  const int tid = threadIdx.x;
  const int lane = tid & 63;
  const int w = tid >> 6;
  const int b = blockIdx.y;
  const int half = blockIdx.z;
  const int u = blockIdx.x * 4 + w;
  const int q4 = 4 * (lane >> 4);
  const int l15 = lane & 15;
  const float* melb = mels + (size_t)b * NMEL * FRAMES;
  for (int idx = tid; idx < 160 * 128; idx += 256) {
    int M = idx & 127;
    int k = idx >> 7;
    int ci = (k < 80) ? k : k - 80;
    int Mp = M + ((k < 80) ? 0 : 1);
    float v = (Mp < 128) ? melb[(size_t)ci * FRAMES + Mp] : 0.f;
    BT[M * BSTR + k] = f2bf(v);
  }
  __syncthreads();
  facc acc[5][4];
  #pragma unroll
  for (int mt = 0; mt < 5; ++mt) {
    facc bi;
    #pragma unroll
    for (int r = 0; r < 4; ++r) bi[r] = mel_b[16 * mt + q4 + r];
    #pragma unroll
    for (int nt = 0; nt < 4; ++nt) acc[mt][nt] = bi;
  }
  const ushort* cA = condA + (size_t)u * 25 * 512 + lane * 8;
  const int bofs = l15 * BSTR + 8 * (lane >> 4);
  #pragma unroll
  for (int kt = 0; kt < 5; ++kt) {
    bfrag a[5];
    #pragma unroll
    for (int mt = 0; mt < 5; ++mt) a[mt] = ldfrag(cA + (mt * 5 + kt) * 512);
    #pragma unroll
    for (int nt = 0; nt < 4; ++nt) {
      bfrag bb = ldfrag(&BT[(half * 64 + nt * 16) * BSTR + bofs + kt * 32]);
      #pragma unroll
      for (int mt = 0; mt < 5; ++mt) acc[mt][nt] = MFMA16(a[mt], bb, acc[mt][nt]);
    }
  }
  ushort* cb = cond + (size_t)b * NMEL * T_LEN;
  #pragma unroll
  for (int mt = 0; mt < 5; ++mt)
    #pragma unroll
    for (int nt = 0; nt < 4; ++nt) {
      const int M = half * 64 + nt * 16 + l15;
      if (M < 127) {
        #pragma unroll
        for (int r = 0; r < 4; ++r)
          cb[(size_t)(16 * mt + q4 + r) * T_LEN + M * 256 + u] =
              f2bf(acc[mt][nt][r]);
      }
    }
}

// ============ cooperative persistent kernel: 2 tiles/block ============
#define XSTR2 152
#define CSTR 104
#define HSTR 72
#define SSTR 152
__global__ __launch_bounds__(256, 2) void wn_coop_kernel(
    const float* __restrict__ x, const float* __restrict__ iw,
    const float* __restrict__ ib, const ushort* __restrict__ cond,
    float* __restrict__ resA, float* __restrict__ resB,
    const ushort* __restrict__ wa, const ushort* __restrict__ wsf,
    const ushort* __restrict__ wrf, const float* __restrict__ zb,
    const float* __restrict__ sbsum, const float* __restrict__ res_b,
    const ushort* __restrict__ wp1, const float* __restrict__ p1b,
    ushort* __restrict__ y1r) {
  __shared__ ushort XTap[64 * XSTR2];   // [t][k 0..127] taps (also ST in epilogue)
  __shared__ ushort CT[2][64 * CSTR];   // cond per tile, [t][k' 0..95] (80..95 = 0)
  __shared__ ushort HT[64 * HSTR];      // [t][ch 0..63]

  cg::grid_group grid = cg::this_grid();

  const int tid = threadIdx.x;
  const int lane = tid & 63;
  const int w = tid >> 6;
  const int b = blockIdx.x & 1;
  const int pair = blockIdx.x >> 1;
  const int q4 = 4 * (lane >> 4);
  const int l15 = lane & 15;
  const size_t bres = (size_t)b * 64 * T_LEN;
  const int t0[2] = {pair * 128, pair * 128 + 64};

  facc rs[2][4];
  facc sk[2][8];

  // ---- prologue ----
  {
    float iwv[4], ibv[4];
    #pragma unroll
    for (int r = 0; r < 4; ++r) {
      iwv[r] = iw[16 * w + q4 + r];
      ibv[r] = ib[16 * w + q4 + r];
    }
    const float* xb = x + (size_t)b * T_LEN;
    float* r0 = resA + bres;
    #pragma unroll
    for (int tau = 0; tau < 2; ++tau) {
      #pragma unroll
      for (int nt = 0; nt < 4; ++nt) {
        const int tt = t0[tau] + nt * 16 + l15;
        float xv = xb[tt];
        #pragma unroll
        for (int r = 0; r < 4; ++r) {
          rs[tau][nt][r] = xv * iwv[r] + ibv[r];
          r0[(size_t)(16 * w + q4 + r) * T_LEN + tt] = rs[tau][nt][r];
        }
      }
      #pragma unroll
      for (int j = 0; j < 8; ++j) {
        #pragma unroll
        for (int r = 0; r < 4; ++r)
          sk[tau][j][r] = sbsum[32 * w + 16 * (j >> 2) + q4 + r];
      }
      // stage cond tile into CT[tau]
      {
        const int t = tid & 63;
        const int kc = tid >> 6;
        const ushort* cgb = cond + (size_t)b * NMEL * T_LEN + t0[tau] + t;
        for (int j = 0; j < 20; ++j) {
          int c = kc * 20 + j;
          CT[tau][t * CSTR + c] = cgb[(size_t)c * T_LEN];
        }
        if (kc == 0) {
          #pragma unroll
          for (int j = 0; j < 16; ++j) CT[tau][t * CSTR + 80 + j] = 0;
        }
      }
    }
  }
  __threadfence();
  grid.sync();

  const int bofs_x = l15 * XSTR2 + 8 * (lane >> 4);
  const int bofs_c = l15 * CSTR + 8 * (lane >> 4);
  const int bofs_h = l15 * HSTR + 8 * (lane >> 4);

  for (int i = 0; i < NBLK; ++i) {
    const int d = 1 << (i % 10);
    const float* rprev = ((i & 1) ? resB : resA) + bres;
    float* rnext = ((i & 1) ? resA : resB) + bres;

    #pragma unroll
    for (int tau = 0; tau < 2; ++tau) {
      // stage tap0 (global, prev layer) k 0..63
      {
        const int t = tid & 63;
        const int kc = tid >> 6;
        const int tm = t0[tau] + t - d;
        us8v v0, v1;
        #pragma unroll
        for (int j = 0; j < 8; ++j) {
          float f0 = (tm >= 0) ? rprev[(size_t)(kc * 16 + j) * T_LEN + tm] : 0.f;
          float f1 = (tm >= 0) ? rprev[(size_t)(kc * 16 + 8 + j) * T_LEN + tm] : 0.f;
          v0[j] = f2bf(f0);
          v1[j] = f2bf(f1);
        }
        *reinterpret_cast<us8v*>(&XTap[t * XSTR2 + kc * 16]) = v0;
        *reinterpret_cast<us8v*>(&XTap[t * XSTR2 + kc * 16 + 8]) = v1;
      }
      // tap1 from res regs, k 64..127
      #pragma unroll
      for (int nt = 0; nt < 4; ++nt) {
        us4v p;
        #pragma unroll
        for (int r = 0; r < 4; ++r) p[r] = f2bf(rs[tau][nt][r]);
        *reinterpret_cast<us4v*>(
            &XTap[(nt * 16 + l15) * XSTR2 + 64 + 16 * w + q4]) = p;
      }
      __syncthreads();

      // phase A: z = Wtap @ Xtap + Wcond @ C
      facc accF[4], accG[4];
      #pragma unroll
      for (int nt = 0; nt < 4; ++nt) {
        #pragma unroll
        for (int r = 0; r < 4; ++r) {
          accF[nt][r] = zb[i * 128 + 16 * w + q4 + r];
          accG[nt][r] = zb[i * 128 + 64 + 16 * w + q4 + r];
        }
      }
      {
        const ushort* wal = wa + (size_t)i * 56 * 512 + lane * 8;
        #pragma unroll
        for (int kt = 0; kt < 7; ++kt) {
          bfrag aF = ldfrag(wal + (w * 7 + kt) * 512);
          bfrag aG = ldfrag(wal + ((w + 4) * 7 + kt) * 512);
          #pragma unroll
          for (int nt = 0; nt < 4; ++nt) {
            bfrag bb = (kt < 4)
                ? ldfrag(&XTap[nt * 16 * XSTR2 + bofs_x + kt * 32])
                : ldfrag(&CT[tau][nt * 16 * CSTR + bofs_c + (kt - 4) * 32]);
            accF[nt] = MFMA16(aF, bb, accF[nt]);
            accG[nt] = MFMA16(aG, bb, accG[nt]);
          }
        }
      }
      // gate -> HT
      #pragma unroll
      for (int nt = 0; nt < 4; ++nt) {
        us4v p;
        #pragma unroll
        for (int r = 0; r < 4; ++r)
          p[r] = f2bf(tanhf_(accF[nt][r]) * sigmoidf_(accG[nt][r]));
        *reinterpret_cast<us4v*>(&HT[(nt * 16 + l15) * HSTR + 16 * w + q4]) = p;
      }
      __syncthreads();

      // skip += Ws@h; res += res_b + Wr@h
      {
        float rbv[4];
        #pragma unroll
        for (int r = 0; r < 4; ++r) rbv[r] = res_b[i * 64 + 16 * w + q4 + r];
        #pragma unroll
        for (int nt = 0; nt < 4; ++nt) {
          #pragma unroll
          for (int r = 0; r < 4; ++r) rs[tau][nt][r] += rbv[r];
        }
        const ushort* wsl = wsf + (size_t)i * 16 * 512 + lane * 8;
        const ushort* wrl = wrf + (size_t)i * 8 * 512 + lane * 8;
        #pragma unroll
        for (int kt = 0; kt < 2; ++kt) {
          bfrag a0 = ldfrag(wsl + ((2 * w) * 2 + kt) * 512);
          bfrag a1 = ldfrag(wsl + ((2 * w + 1) * 2 + kt) * 512);
          bfrag ar = ldfrag(wrl + (w * 2 + kt) * 512);
          #pragma unroll
          for (int nt = 0; nt < 4; ++nt) {
            bfrag bb = ldfrag(&HT[nt * 16 * HSTR + bofs_h + kt * 32]);
            sk[tau][nt]     = MFMA16(a0, bb, sk[tau][nt]);
            sk[tau][4 + nt] = MFMA16(a1, bb, sk[tau][4 + nt]);
            rs[tau][nt]     = MFMA16(ar, bb, rs[tau][nt]);
          }
        }
      }
      // publish res
      #pragma unroll
      for (int nt = 0; nt < 4; ++nt) {
        const int tt = t0[tau] + nt * 16 + l15;
        #pragma unroll
        for (int r = 0; r < 4; ++r)
          rnext[(size_t)(16 * w + q4 + r) * T_LEN + tt] = rs[tau][nt][r];
      }
      __syncthreads();  // protect XTap/HT reuse by next tau
    }
    __threadfence();
    grid.sync();
  }

  // ---- fused post1 per tile ----
  ushort* ST = XTap;  // stride SSTR == XSTR2
  #pragma unroll
  for (int tau = 0; tau < 2; ++tau) {
    #pragma unroll
    for (int j = 0; j < 8; ++j) {
      us4v p;
      #pragma unroll
      for (int r = 0; r < 4; ++r) p[r] = f2bf(fmaxf(sk[tau][j][r], 0.f));
      *reinterpret_cast<us4v*>(
          &ST[((j & 3) * 16 + l15) * SSTR + 32 * w + 16 * (j >> 2) + q4]) = p;
    }
    __syncthreads();
    facc acc[4][4];
    #pragma unroll
    for (int mi = 0; mi < 4; ++mi) {
      #pragma unroll
      for (int nt = 0; nt < 4; ++nt) {
        #pragma unroll
        for (int r = 0; r < 4; ++r)
          acc[mi][nt][r] = p1b[16 * (4 * w + mi) + q4 + r];
      }
    }
    {
      const int bofs_s = l15 * SSTR + 8 * (lane >> 4);
      const ushort* wpl = wp1 + lane * 8;
      #pragma unroll
      for (int kt = 0; kt < 4; ++kt) {
        bfrag a[4];
        #pragma unroll
        for (int mi = 0; mi < 4; ++mi)
          a[mi] = ldfrag(wpl + ((4 * w + mi) * 4 + kt) * 512);
        #pragma unroll
        for (int nt = 0; nt < 4; ++nt) {
          bfrag bb = ldfrag(&ST[nt * 16 * SSTR + bofs_s + kt * 32]);
          #pragma unroll
          for (int mi = 0; mi < 4; ++mi)
            acc[mi][nt] = MFMA16(a[mi], bb, acc[mi][nt]);
        }
      }
    }
    ushort* yb = y1r + (size_t)b * 256 * T_LEN;
    #pragma unroll
    for (int mi = 0; mi < 4; ++mi) {
      #pragma unroll
      for (int nt = 0; nt < 4; ++nt) {
        const int tt = t0[tau] + nt * 16 + l15;
        #pragma unroll
        for (int r = 0; r < 4; ++r)
          yb[(size_t)(16 * (4 * w + mi) + q4 + r) * T_LEN + tt] =
              f2bf(fmaxf(acc[mi][nt][r], 0.f));
      }
    }
    __syncthreads();  // protect ST reuse
  }
}

// ============ fallback path (round-2 verified kernels) ============
__global__ __launch_bounds__(256) void init_res_kernel(
    const float* __restrict__ x, const float* __restrict__ iw,
    const float* __restrict__ ib, float* __restrict__ res) {
  int idx = blockIdx.x * blockDim.x + threadIdx.x;
  if (idx >= BATCH * 64 * T_LEN) return;
  int t = idx % T_LEN;
  int c = (idx / T_LEN) % 64;
  int b = idx / (T_LEN * 64);
  res[idx] = x[(size_t)b * T_LEN + t] * iw[c] + ib[c];
}

#define FXSTR 232
#define FHSTR 72
__global__ __launch_bounds__(256) void wn_mfma_kernel(
    const float* __restrict__ res_in, float* __restrict__ res_out,
    const ushort* __restrict__ cond, float* __restrict__ skip,
    const ushort* __restrict__ wa, const ushort* __restrict__ wsf,
    const ushort* __restrict__ wrf, const float* __restrict__ zb,
    const float* __restrict__ skip_b, const float* __restrict__ res_b,
    int blk, int dil) {
  __shared__ ushort XT[64 * FXSTR];
  __shared__ ushort HT[64 * FHSTR];
  const int tid = threadIdx.x;
  const int lane = tid & 63;
  const int w = tid >> 6;
  const int t0 = blockIdx.x * 64;
  const int b = blockIdx.y;
  const float* rb = res_in + (size_t)b * 64 * T_LEN;
  const ushort* cb = cond + (size_t)b * NMEL * T_LEN;
  {
    const int t = t0 + lane;
    const int tm = t - dil;
    for (int kc = 0; kc < 7; ++kc) {
      const int k0 = w * 56 + kc * 8;
      us8v v;
      if (k0 < 64) {
        #pragma unroll
        for (int j = 0; j < 8; ++j) {
          float f = (tm >= 0) ? rb[(size_t)(k0 + j) * T_LEN + tm] : 0.f;
          v[j] = f2bf(f);
        }
      } else if (k0 < 128) {
        #pragma unroll
        for (int j = 0; j < 8; ++j) v[j] = f2bf(rb[(size_t)(k0 - 64 + j) * T_LEN + t]);
      } else if (k0 < 208) {
        #pragma unroll
        for (int j = 0; j < 8; ++j) v[j] = cb[(size_t)(k0 - 128 + j) * T_LEN + t];
      } else {
        #pragma unroll
        for (int j = 0; j < 8; ++j) v[j] = 0;
      }
      *reinterpret_cast<us8v*>(&XT[lane * FXSTR + k0]) = v;
    }
  }
  __syncthreads();
  facc accF[4], accG[4];
  {
    const int q4 = 4 * (lane >> 4);
    #pragma unroll
    for (int nt = 0; nt < 4; ++nt) {
      #pragma unroll
      for (int r = 0; r < 4; ++r) {
        accF[nt][r] = zb[blk * 128 + 16 * w + q4 + r];
        accG[nt][r] = zb[blk * 128 + 64 + 16 * w + q4 + r];
      }
    }
  }
  {
    const ushort* wal = wa + (size_t)blk * 56 * 512;
    const int lo = lane * 8;
    const int bofs = (lane & 15) * FXSTR + 8 * (lane >> 4);
    #pragma unroll
    for (int kt = 0; kt < 7; ++kt) {
      bfrag aF = ldfrag(wal + (w * 7 + kt) * 512 + lo);
      bfrag aG = ldfrag(wal + ((w + 4) * 7 + kt) * 512 + lo);
      #pragma unroll
      for (int nt = 0; nt < 4; ++nt) {
        bfrag bb = ldfrag(&XT[nt * 16 * FXSTR + bofs + kt * 32]);
        accF[nt] = MFMA16(aF, bb, accF[nt]);
        accG[nt] = MFMA16(aG, bb, accG[nt]);
      }
    }
  }
  {
    const int ch = 16 * w + 4 * (lane >> 4);
    #pragma unroll
    for (int nt = 0; nt < 4; ++nt) {
      us4v p;
      #pragma unroll
      for (int r = 0; r < 4; ++r)
        p[r] = f2bf(tanhf_(accF[nt][r]) * sigmoidf_(accG[nt][r]));
      *reinterpret_cast<us4v*>(&HT[(nt * 16 + (lane & 15)) * FHSTR + ch]) = p;
    }
  }
  __syncthreads();
  facc accS0[4], accS1[4], accR[4];
  {
    const int q4 = 4 * (lane >> 4);
    #pragma unroll
    for (int nt = 0; nt < 4; ++nt) {
      #pragma unroll
      for (int r = 0; r < 4; ++r) {
        accS0[nt][r] = skip_b[blk * 128 + 32 * w + q4 + r];
        accS1[nt][r] = skip_b[blk * 128 + 32 * w + 16 + q4 + r];
        accR[nt][r]  = res_b[blk * 64 + 16 * w + q4 + r];
      }
    }
  }
  {
    const ushort* wsl = wsf + (size_t)blk * 16 * 512;
    const ushort* wrl = wrf + (size_t)blk * 8 * 512;
    const int lo = lane * 8;
    const int bofs = (lane & 15) * FHSTR + 8 * (lane >> 4);
    #pragma unroll
    for (int kt = 0; kt < 2; ++kt) {
      bfrag a0 = ldfrag(wsl + ((2 * w) * 2 + kt) * 512 + lo);
      bfrag a1 = ldfrag(wsl + ((2 * w + 1) * 2 + kt) * 512 + lo);
      bfrag ar = ldfrag(wrl + (w * 2 + kt) * 512 + lo);
      #pragma unroll
      for (int nt = 0; nt < 4; ++nt) {
        bfrag bb = ldfrag(&HT[nt * 16 * FHSTR + bofs + kt * 32]);
        accS0[nt] = MFMA16(a0, bb, accS0[nt]);
        accS1[nt] = MFMA16(a1, bb, accS1[nt]);
        accR[nt]  = MFMA16(ar, bb, accR[nt]);
      }
    }
  }
  {
    float* sg = skip + (size_t)b * 128 * T_LEN;
    float* ro = res_out + (size_t)b * 64 * T_LEN;
    const int q4 = 4 * (lane >> 4);
    #pragma unroll
    for (int nt = 0; nt < 4; ++nt) {
      const int tt = t0 + nt * 16 + (lane & 15);
      #pragma unroll
      for (int r = 0; r < 4; ++r) {
        sg[(size_t)(32 * w + q4 + r) * T_LEN + tt] += accS0[nt][r];
        sg[(size_t)(32 * w + 16 + q4 + r) * T_LEN + tt] += accS1[nt][r];
        float rv = rb[(size_t)(16 * w + q4 + r) * T_LEN + tt];
        ro[(size_t)(16 * w + q4 + r) * T_LEN + tt] = rv + accR[nt][r];
      }
    }
  }
}

#define FSSTR 136
__global__ __launch_bounds__(256) void post1_mfma(
    const float* __restrict__ skip, const ushort* __restrict__ wp1,
    const float* __restrict__ p1b, ushort* __restrict__ y1r) {
  __shared__ ushort ST[64 * FSSTR];
  const int tid = threadIdx.x;
  const int lane = tid & 63;
  const int w = tid >> 6;
  const int t0 = blockIdx.x * 64;
  const int b = blockIdx.y;
  const float* sb = skip + (size_t)b * 128 * T_LEN;
  const int t = t0 + lane;
  for (int kc = 0; kc < 4; ++kc) {
    int k0 = w * 32 + kc * 8;
    us8v v;
    #pragma unroll
    for (int j = 0; j < 8; ++j)
      v[j] = f2bf(fmaxf(sb[(size_t)(k0 + j) * T_LEN + t], 0.f));
    *reinterpret_cast<us8v*>(&ST[lane * FSSTR + k0]) = v;
  }
  __syncthreads();
  const int q4 = 4 * (lane >> 4);
  facc acc[4][4];
  #pragma unroll
  for (int mi = 0; mi < 4; ++mi) {
    #pragma unroll
    for (int nt = 0; nt < 4; ++nt) {
      #pragma unroll
      for (int r = 0; r < 4; ++r)
        acc[mi][nt][r] = p1b[16 * (4 * w + mi) + q4 + r];
    }
  }
  const int lo = lane * 8;
  const int bofs = (lane & 15) * FSSTR + 8 * (lane >> 4);
  #pragma unroll
  for (int kt = 0; kt < 4; ++kt) {
    bfrag a[4];
    #pragma unroll
    for (int mi = 0; mi < 4; ++mi)
      a[mi] = ldfrag(wp1 + ((4 * w + mi) * 4 + kt) * 512 + lo);
    #pragma unroll
    for (int nt = 0; nt < 4; ++nt) {
      bfrag bb = ldfrag(&ST[nt * 16 * FSSTR + bofs + kt * 32]);
      #pragma unroll
      for (int mi = 0; mi < 4; ++mi) acc[mi][nt] = MFMA16(a[mi], bb, acc[mi][nt]);
    }
  }
  ushort* yb = y1r + (size_t)b * 256 * T_LEN;
  #pragma unroll
  for (int mi = 0; mi < 4; ++mi) {
    #pragma unroll
    for (int nt = 0; nt < 4; ++nt) {
      const int tt = t0 + nt * 16 + (lane & 15);
      #pragma unroll
      for (int r = 0; r < 4; ++r)
        yb[(size_t)(16 * (4 * w + mi) + q4 + r) * T_LEN + tt] =
            f2bf(fmaxf(acc[mi][nt][r], 0.f));
    }
  }
}

// ---- post2: out = p2_w @ y1r + b (fp32) ----
#define YSTR 264
__global__ __launch_bounds__(256) void post2_mfma(
    const ushort* __restrict__ y1r, const ushort* __restrict__ wp2,
    const float* __restrict__ p2b, float* __restrict__ out) {
  __shared__ ushort YT[64 * YSTR];
  const int tid = threadIdx.x;
  const int lane = tid & 63;
  const int w = tid >> 6;
  const int t0 = blockIdx.x * 64;
  const int b = blockIdx.y;
  const ushort* yb = y1r + (size_t)b * 256 * T_LEN;
  const int t = t0 + lane;
  for (int kc = 0; kc < 8; ++kc) {
    int k0 = w * 64 + kc * 8;
    us8v v;
    #pragma unroll
    for (int j = 0; j < 8; ++j) v[j] = yb[(size_t)(k0 + j) * T_LEN + t];
    *reinterpret_cast<us8v*>(&YT[lane * YSTR + k0]) = v;
  }
  __syncthreads();
  const int q4 = 4 * (lane >> 4);
  facc acc[4][4];
  #pragma unroll
  for (int mi = 0; mi < 4; ++mi) {
    #pragma unroll
    for (int nt = 0; nt < 4; ++nt) {
      #pragma unroll
      for (int r = 0; r < 4; ++r)
        acc[mi][nt][r] = p2b[16 * (4 * w + mi) + q4 + r];
    }
  }
  const int lo = lane * 8;
  const int bofs = (lane & 15) * YSTR + 8 * (lane >> 4);
  #pragma unroll
  for (int kt = 0; kt < 8; ++kt) {
    bfrag a[4];
    #pragma unroll
    for (int mi = 0; mi < 4; ++mi)
      a[mi] = ldfrag(wp2 + ((4 * w + mi) * 8 + kt) * 512 + lo);
    #pragma unroll
    for (int nt = 0; nt < 4; ++nt) {
      bfrag bb = ldfrag(&YT[nt * 16 * YSTR + bofs + kt * 32]);
      #pragma unroll
      for (int mi = 0; mi < 4; ++mi) acc[mi][nt] = MFMA16(a[mi], bb, acc[mi][nt]);
    }
  }
  float* ob = out + (size_t)b * 256 * T_LEN;
  #pragma unroll
  for (int mi = 0; mi < 4; ++mi) {
    #pragma unroll
    for (int nt = 0; nt < 4; ++nt) {
      const int tt = t0 + nt * 16 + (lane & 15);
      #pragma unroll
      for (int r = 0; r < 4; ++r)
        ob[(size_t)(16 * (4 * w + mi) + q4 + r) * T_LEN + tt] = acc[mi][nt][r];
    }
  }
}

extern "C" void kernel_launch(void* const* d_in, const int* in_sizes, int n_in,
                              void* d_out, int out_size, void* d_ws,
                              size_t ws_size, hipStream_t stream) {
  const float* x       = (const float*)d_in[0];
  const float* mels    = (const float*)d_in[1];
  const float* input_w = (const float*)d_in[2];
  const float* input_b = (const float*)d_in[3];
  const float* mel_w   = (const float*)d_in[4];
  const float* mel_b   = (const float*)d_in[5];
  const float* dil_w   = (const float*)d_in[6];
  const float* dil_b   = (const float*)d_in[7];
  const float* cond_w  = (const float*)d_in[8];
  const float* cond_b  = (const float*)d_in[9];
  const float* skip_w  = (const float*)d_in[10];
  const float* skip_b  = (const float*)d_in[11];
  const float* res_w   = (const float*)d_in[12];
  const float* res_b   = (const float*)d_in[13];
  const float* p1_w    = (const float*)d_in[14];
  const float* p1_b    = (const float*)d_in[15];
  const float* p2_w    = (const float*)d_in[16];
  const float* p2_b    = (const float*)d_in[17];

  char* ws = (char*)d_ws;
  float* res0   = (float*)(ws + RES0_OFF);
  float* res1   = (float*)(ws + RES1_OFF);
  ushort* condp = (ushort*)(ws + COND_OFF);
  ushort* wa    = (ushort*)(ws + WA_OFF);
  ushort* wsf   = (ushort*)(ws + WSF_OFF);
  ushort* wrf   = (ushort*)(ws + WRF_OFF);
  ushort* wp1   = (ushort*)(ws + WP1_OFF);
  ushort* wp2   = (ushort*)(ws + WP2_OFF);
  ushort* condA = (ushort*)(ws + CONDA_OFF);
  float* zbp    = (float*)(ws + ZB_OFF);
  float* sbsp   = (float*)(ws + SBS_OFF);
  float* skipg  = (float*)(ws + SKIPG_OFF);
  ushort* y1rp  = (ushort*)(ws + Y1R_OFF);
  float* out    = (float*)d_out;

  prep_kernel<<<2048, 256, 0, stream>>>(dil_w, cond_w, skip_w, res_w, p1_w,
                                        p2_w, mel_w, dil_b, cond_b, skip_b, wa,
                                        wsf, wrf, wp1, wp2, condA, zbp, sbsp);
  cond_mfma<<<dim3(64, BATCH, 2), 256, 0, stream>>>(mels, condA, mel_b, condp);

  void* args[] = {(void*)&x,     (void*)&input_w, (void*)&input_b,
                  (void*)&condp, (void*)&res0,    (void*)&res1,
                  (void*)&wa,    (void*)&wsf,     (void*)&wrf,
                  (void*)&zbp,   (void*)&sbsp,    (void*)&res_b,
                  (void*)&wp1,   (void*)&p1_b,    (void*)&y1rp};
  hipError_t ce = hipLaunchCooperativeKernel(
      (const void*)wn_coop_kernel, dim3(NPAIR * BATCH), dim3(256), args, 0,
      stream);

  if (ce != hipSuccess) {
    // ---- fallback: per-layer kernels (round-2 verified path) ----
    init_res_kernel<<<(BATCH * 64 * T_LEN + 255) / 256, 256, 0, stream>>>(
        x, input_w, input_b, res0);
    hipMemsetAsync(skipg, 0, (size_t)BATCH * 128 * T_LEN * sizeof(float),
                   stream);
    float* rin = res0;
    float* rout = res1;
    for (int i = 0; i < NBLK; ++i) {
      int d = 1 << (i % 10);
      wn_mfma_kernel<<<dim3(NTILES, BATCH), 256, 0, stream>>>(
          rin, rout, condp, skipg, wa, wsf, wrf, zbp, skip_b, res_b, i, d);
      float* tmp = rin; rin = rout; rout = tmp;
    }
    post1_mfma<<<dim3(NTILES, BATCH), 256, 0, stream>>>(skipg, wp1, p1_b, y1rp);
  }

  post2_mfma<<<dim3(NTILES, BATCH), 256, 0, stream>>>(y1rp, wp2, p2_b, out);
}

// Round 5
// 1203.897 us; speedup vs baseline: 3.3247x; 3.3247x over previous
//
#include <hip/hip_runtime.h>
#include <math.h>

#define T_LEN 32512
#define NTILES 508
#define BATCH 2
#define NMEL 80
#define FRAMES 128
#define NBLK 30
#define NPAIRS 15

typedef short bfrag __attribute__((ext_vector_type(8)));
typedef float facc __attribute__((ext_vector_type(4)));
typedef ushort us4v __attribute__((ext_vector_type(4)));
typedef ushort us8v __attribute__((ext_vector_type(8)));

#define MFMA16(a, b, c) __builtin_amdgcn_mfma_f32_16x16x32_bf16((a), (b), (c), 0, 0, 0)

// ---- workspace layout (byte offsets) ----
#define RES0_OFF   0u          // fp32 [2][64][T]  16,646,144
#define RES1_OFF   16646144u   // fp32 [2][64][T]
#define COND_OFF   33292288u   // bf16 [2][80][T]  10,403,840
#define WA_OFF     43696128u   // bf16 30*56*512
#define WSF_OFF    45416448u   // bf16 30*16*512
#define WRF_OFF    45907968u   // bf16 30*8*512
#define WP1_OFF    46153728u   // bf16 64*512
#define WP2_OFF    46219264u   // bf16 128*512
#define CONDA_OFF  46350336u   // bf16 256*25*512
#define ZB_OFF     52903936u   // f32 30*128
#define SBS_OFF    52919296u   // f32 128
#define SKIPG_OFF  52919808u   // f32 [2][128][T]  33,292,288
#define Y1R_OFF    0u          // bf16 [2][256][T] aliases RES0+RES1 (dead after loop)
// total ~86.2 MB

static __device__ __forceinline__ ushort f2bf(float f) {
  union { float f; unsigned int u; } v;
  v.f = f;
  unsigned int r = (v.u + 0x7FFFu + ((v.u >> 16) & 1u)) >> 16;
  return (ushort)r;
}
static __device__ __forceinline__ float sigmoidf_(float x) {
  return 1.f / (1.f + __expf(-x));
}
static __device__ __forceinline__ float tanhf_(float x) {
  return 2.f / (1.f + __expf(-2.f * x)) - 1.f;
}
static __device__ __forceinline__ bfrag ldfrag(const ushort* p) {
  return *reinterpret_cast<const bfrag*>(p);
}

// ---- prep: all weights into MFMA A-fragment bf16 + condA + bias precomps ----
__global__ __launch_bounds__(256) void prep_kernel(
    const float* __restrict__ dil_w, const float* __restrict__ cond_w,
    const float* __restrict__ skip_w, const float* __restrict__ res_w,
    const float* __restrict__ p1_w, const float* __restrict__ p2_w,
    const float* __restrict__ mel_w, const float* __restrict__ dil_b,
    const float* __restrict__ cond_b,
    ushort* __restrict__ wa, ushort* __restrict__ wsf, ushort* __restrict__ wrf,
    ushort* __restrict__ wp1, ushort* __restrict__ wp2,
    ushort* __restrict__ condA, float* __restrict__ zb) {
  int tid = blockIdx.x * blockDim.x + threadIdx.x;
  int stride = gridDim.x * blockDim.x;
  // W_all[layer][128 m][224 k]: k<64 dil tap0; k<128 dil tap1; k<208 cond; else 0
  for (int idx = tid; idx < NBLK * 56 * 512; idx += stride) {
    int j = idx & 7, lane = (idx >> 3) & 63;
    int f = (idx >> 9) % 56, layer = idx / (56 * 512);
    int mt = f / 7, kt = f % 7;
    int m = 16 * mt + (lane & 15);
    int k = 32 * kt + 8 * (lane >> 4) + j;
    float v;
    if (k < 64)       v = dil_w[(((size_t)layer * 128 + m) * 64 + k) * 2 + 0];
    else if (k < 128) v = dil_w[(((size_t)layer * 128 + m) * 64 + (k - 64)) * 2 + 1];
    else if (k < 208) v = cond_w[((size_t)layer * 128 + m) * 80 + (k - 128)];
    else              v = 0.f;
    wa[idx] = f2bf(v);
  }
  for (int idx = tid; idx < NBLK * 16 * 512; idx += stride) {
    int j = idx & 7, lane = (idx >> 3) & 63;
    int f = (idx >> 9) & 15, layer = idx / (16 * 512);
    int mt = f >> 1, kt = f & 1;
    int m = 16 * mt + (lane & 15);
    int k = 32 * kt + 8 * (lane >> 4) + j;
    wsf[idx] = f2bf(skip_w[((size_t)layer * 128 + m) * 64 + k]);
  }
  for (int idx = tid; idx < NBLK * 8 * 512; idx += stride) {
    int j = idx & 7, lane = (idx >> 3) & 63;
    int f = (idx >> 9) & 7, layer = idx / (8 * 512);
    int mt = f >> 1, kt = f & 1;
    int m = 16 * mt + (lane & 15);
    int k = 32 * kt + 8 * (lane >> 4) + j;
    wrf[idx] = f2bf(res_w[((size_t)layer * 64 + m) * 64 + k]);
  }
  for (int idx = tid; idx < 64 * 512; idx += stride) {
    int j = idx & 7, lane = (idx >> 3) & 63;
    int f = idx >> 9;
    int mt = f >> 2, kt = f & 3;
    int m = 16 * mt + (lane & 15);
    int k = 32 * kt + 8 * (lane >> 4) + j;
    wp1[idx] = f2bf(p1_w[(size_t)m * 128 + k]);
  }
  for (int idx = tid; idx < 128 * 512; idx += stride) {
    int j = idx & 7, lane = (idx >> 3) & 63;
    int f = idx >> 9;
    int mt = f >> 3, kt = f & 7;
    int m = 16 * mt + (lane & 15);
    int k = 32 * kt + 8 * (lane >> 4) + j;
    wp2[idx] = f2bf(p2_w[(size_t)m * 256 + k]);
  }
  // condA[u][f=mt*5+kt][512]: A_u[m=c(80)][k(160)]
  for (int idx = tid; idx < 25 * 512 * 256; idx += stride) {
    int u = idx & 255;
    int e = idx >> 8;
    int j = e & 7, lane = (e >> 3) & 63, f = e >> 9;
    int mt = f / 5, kt = f % 5;
    int m = 16 * mt + (lane & 15);
    int k = 32 * kt + 8 * (lane >> 4) + j;
    int ci = (k < 80) ? k : k - 80;
    int kk = (k < 80) ? (255 - u) : (511 - u);
    condA[((size_t)u * 25 + f) * 512 + lane * 8 + j] =
        f2bf(mel_w[((size_t)m * 80 + ci) * 512 + kk]);
  }
  for (int idx = tid; idx < NBLK * 128; idx += stride)
    zb[idx] = dil_b[idx] + cond_b[idx];
}

// ---- mel upsample as MFMA GEMM per u ----
#define BSTR 168
__global__ __launch_bounds__(256) void cond_mfma(
    const float* __restrict__ mels, const ushort* __restrict__ condA,
    const float* __restrict__ mel_b, ushort* __restrict__ cond) {
  __shared__ ushort BT[128 * BSTR];
  const int tid = threadIdx.x;
  const int lane = tid & 63;
  const int w = tid >> 6;
  const int b = blockIdx.y;
  const int half = blockIdx.z;
  const int u = blockIdx.x * 4 + w;
  const int q4 = 4 * (lane >> 4);
  const int l15 = lane & 15;
  const float* melb = mels + (size_t)b * NMEL * FRAMES;
  for (int idx = tid; idx < 160 * 128; idx += 256) {
    int M = idx & 127;
    int k = idx >> 7;
    int ci = (k < 80) ? k : k - 80;
    int Mp = M + ((k < 80) ? 0 : 1);
    float v = (Mp < 128) ? melb[(size_t)ci * FRAMES + Mp] : 0.f;
    BT[M * BSTR + k] = f2bf(v);
  }
  __syncthreads();
  facc acc[5][4];
  #pragma unroll
  for (int mt = 0; mt < 5; ++mt) {
    #pragma unroll
    for (int nt = 0; nt < 4; ++nt) {
      #pragma unroll
      for (int r = 0; r < 4; ++r) acc[mt][nt][r] = mel_b[16 * mt + q4 + r];
    }
  }
  const ushort* cA = condA + (size_t)u * 25 * 512 + lane * 8;
  const int bofs = l15 * BSTR + 8 * (lane >> 4);
  #pragma unroll
  for (int kt = 0; kt < 5; ++kt) {
    bfrag a[5];
    #pragma unroll
    for (int mt = 0; mt < 5; ++mt) a[mt] = ldfrag(cA + (mt * 5 + kt) * 512);
    #pragma unroll
    for (int nt = 0; nt < 4; ++nt) {
      bfrag bb = ldfrag(&BT[(half * 64 + nt * 16) * BSTR + bofs + kt * 32]);
      #pragma unroll
      for (int mt = 0; mt < 5; ++mt) acc[mt][nt] = MFMA16(a[mt], bb, acc[mt][nt]);
    }
  }
  ushort* cb = cond + (size_t)b * NMEL * T_LEN;
  #pragma unroll
  for (int mt = 0; mt < 5; ++mt)
    #pragma unroll
    for (int nt = 0; nt < 4; ++nt) {
      const int M = half * 64 + nt * 16 + l15;
      if (M < 127) {
        #pragma unroll
        for (int r = 0; r < 4; ++r)
          cb[(size_t)(16 * mt + q4 + r) * T_LEN + M * 256 + u] =
              f2bf(acc[mt][nt][r]);
      }
    }
}

__global__ __launch_bounds__(256) void init_res_kernel(
    const float* __restrict__ x, const float* __restrict__ iw,
    const float* __restrict__ ib, float* __restrict__ res) {
  int idx = blockIdx.x * blockDim.x + threadIdx.x;
  if (idx >= BATCH * 64 * T_LEN) return;
  int t = idx % T_LEN;
  int c = (idx / T_LEN) % 64;
  int b = idx / (T_LEN * 64);
  res[idx] = x[(size_t)b * T_LEN + t] * iw[c] + ib[c];
}

// ============ pair kernel: layers (i0, i0+1), shifted-tile recompute ============
// Block computes layer i0 on tile t0-d1 (shifted) and t0 (home), keeps both
// res_i0 results in regs, then layer i0+1 on home with taps from regs.
// skip contributions of BOTH layers accumulate in regs -> one global RMW.
#define XSTR 136
#define CSTR 104
#define HSTR 72
__global__ __launch_bounds__(256, 4) void wn_pair_kernel(
    const float* __restrict__ res_in, float* __restrict__ res_out,
    const ushort* __restrict__ cond, float* __restrict__ skip,
    const ushort* __restrict__ wa, const ushort* __restrict__ wsf,
    const ushort* __restrict__ wrf, const float* __restrict__ zb,
    const float* __restrict__ skip_b, const float* __restrict__ res_b,
    int i0, int d0) {
  __shared__ ushort XT[64 * XSTR];  // [t][k 0..127] taps
  __shared__ ushort CT[64 * CSTR];  // [t][0..79 cond, 80..95 zero]
  __shared__ ushort HT[64 * HSTR];  // [t][ch 0..63]

  const int i1 = i0 + 1;
  const int d1 = d0 * 2;
  const int tid = threadIdx.x;
  const int lane = tid & 63;
  const int w = tid >> 6;
  const int l15 = lane & 15;
  const int q4 = 4 * (lane >> 4);
  const int b = blockIdx.y;
  const int t0 = blockIdx.x * 64;
  const int t0s = t0 - d1;

  const float* rb = res_in + (size_t)b * 64 * T_LEN;
  const ushort* cbase = cond + (size_t)b * NMEL * T_LEN;
  const int bofs_x = l15 * XSTR + 8 * (lane >> 4);
  const int bofs_c = l15 * CSTR + 8 * (lane >> 4);
  const int bofs_h = l15 * HSTR + 8 * (lane >> 4);

  facc rs_s[4], rs_h[4], sk[8];
  #pragma unroll
  for (int j = 0; j < 8; ++j) {
    const int ch = 32 * w + 16 * (j >> 2) + q4;
    #pragma unroll
    for (int r = 0; r < 4; ++r)
      sk[j][r] = skip_b[i0 * 128 + ch + r] + skip_b[i1 * 128 + ch + r];
  }

  // -------- per-context helpers as macros over (TB, RSREG, DOSKIP) --------
#define STAGE_TAPS(TB)                                                        \
  {                                                                           \
    const int t = lane;                                                       \
    const int ta = (TB) + t;                                                  \
    const int tm = ta - d0;                                                   \
    us8v v0a, v0b, v1a, v1b;                                                  \
    _Pragma("unroll")                                                         \
    for (int j = 0; j < 8; ++j) {                                             \
      v0a[j] = (tm >= 0) ? f2bf(rb[(size_t)(16 * w + j) * T_LEN + tm]) : 0;   \
      v0b[j] = (tm >= 0) ? f2bf(rb[(size_t)(16 * w + 8 + j) * T_LEN + tm]) : 0;\
      v1a[j] = (ta >= 0) ? f2bf(rb[(size_t)(16 * w + j) * T_LEN + ta]) : 0;   \
      v1b[j] = (ta >= 0) ? f2bf(rb[(size_t)(16 * w + 8 + j) * T_LEN + ta]) : 0;\
    }                                                                         \
    *reinterpret_cast<us8v*>(&XT[t * XSTR + 16 * w]) = v0a;                   \
    *reinterpret_cast<us8v*>(&XT[t * XSTR + 16 * w + 8]) = v0b;               \
    *reinterpret_cast<us8v*>(&XT[t * XSTR + 64 + 16 * w]) = v1a;              \
    *reinterpret_cast<us8v*>(&XT[t * XSTR + 64 + 16 * w + 8]) = v1b;          \
  }

#define STAGE_COND(TB)                                                        \
  {                                                                           \
    const int t = lane;                                                       \
    const int tg = (TB) + t;                                                  \
    for (int jj = 0; jj < 24; ++jj) {                                         \
      int c = 24 * w + jj;                                                    \
      CT[t * CSTR + c] =                                                      \
          (c < 80 && tg >= 0) ? cbase[(size_t)c * T_LEN + tg] : (ushort)0;    \
    }                                                                         \
  }

#define Z_GATE(LAYER)                                                         \
  {                                                                           \
    facc accF[4], accG[4];                                                    \
    _Pragma("unroll")                                                         \
    for (int nt = 0; nt < 4; ++nt) {                                          \
      _Pragma("unroll")                                                       \
      for (int r = 0; r < 4; ++r) {                                           \
        accF[nt][r] = zb[(LAYER) * 128 + 16 * w + q4 + r];                    \
        accG[nt][r] = zb[(LAYER) * 128 + 64 + 16 * w + q4 + r];               \
      }                                                                       \
    }                                                                         \
    const ushort* wal = wa + (size_t)(LAYER) * 56 * 512 + lane * 8;           \
    _Pragma("unroll")                                                         \
    for (int kt = 0; kt < 7; ++kt) {                                          \
      bfrag aF = ldfrag(wal + (w * 7 + kt) * 512);                            \
      bfrag aG = ldfrag(wal + ((w + 4) * 7 + kt) * 512);                      \
      _Pragma("unroll")                                                       \
      for (int nt = 0; nt < 4; ++nt) {                                        \
        bfrag bb = (kt < 4)                                                   \
            ? ldfrag(&XT[nt * 16 * XSTR + bofs_x + kt * 32])                  \
            : ldfrag(&CT[nt * 16 * CSTR + bofs_c + (kt - 4) * 32]);           \
        accF[nt] = MFMA16(aF, bb, accF[nt]);                                  \
        accG[nt] = MFMA16(aG, bb, accG[nt]);                                  \
      }                                                                       \
    }                                                                         \
    _Pragma("unroll")                                                         \
    for (int nt = 0; nt < 4; ++nt) {                                          \
      us4v p;                                                                 \
      _Pragma("unroll")                                                       \
      for (int r = 0; r < 4; ++r)                                             \
        p[r] = f2bf(tanhf_(accF[nt][r]) * sigmoidf_(accG[nt][r]));            \
      *reinterpret_cast<us4v*>(&HT[(nt * 16 + l15) * HSTR + 16 * w + q4]) = p;\
    }                                                                         \
  }

#define RES_GEMM(LAYER, RSREG)                                                \
  {                                                                           \
    const ushort* wrl = wrf + (size_t)(LAYER) * 8 * 512 + lane * 8;           \
    _Pragma("unroll")                                                         \
    for (int kt = 0; kt < 2; ++kt) {                                          \
      bfrag ar = ldfrag(wrl + (w * 2 + kt) * 512);                            \
      _Pragma("unroll")                                                       \
      for (int nt = 0; nt < 4; ++nt) {                                        \
        bfrag bb = ldfrag(&HT[nt * 16 * HSTR + bofs_h + kt * 32]);            \
        RSREG[nt] = MFMA16(ar, bb, RSREG[nt]);                                \
      }                                                                       \
    }                                                                         \
  }

#define SKIP_GEMM(LAYER)                                                      \
  {                                                                           \
    const ushort* wsl = wsf + (size_t)(LAYER) * 16 * 512 + lane * 8;          \
    _Pragma("unroll")                                                         \
    for (int kt = 0; kt < 2; ++kt) {                                          \
      bfrag a0 = ldfrag(wsl + ((2 * w) * 2 + kt) * 512);                      \
      bfrag a1 = ldfrag(wsl + ((2 * w + 1) * 2 + kt) * 512);                  \
      _Pragma("unroll")                                                       \
      for (int nt = 0; nt < 4; ++nt) {                                        \
        bfrag bb = ldfrag(&HT[nt * 16 * HSTR + bofs_h + kt * 32]);            \
        sk[nt]     = MFMA16(a0, bb, sk[nt]);                                  \
        sk[4 + nt] = MFMA16(a1, bb, sk[4 + nt]);                              \
      }                                                                       \
    }                                                                         \
  }

  // ===== ctx S: layer i0 at shifted tile =====
  STAGE_TAPS(t0s)
  STAGE_COND(t0s)
  __syncthreads();
  Z_GATE(i0)
  __syncthreads();
  // rs_s init = res_{i0-1}(shifted tap1) + res_b[i0]  (fp32, C-layout read)
  #pragma unroll
  for (int nt = 0; nt < 4; ++nt) {
    const int tg = t0s + nt * 16 + l15;
    #pragma unroll
    for (int r = 0; r < 4; ++r) {
      float v = (tg >= 0) ? rb[(size_t)(16 * w + q4 + r) * T_LEN + tg] : 0.f;
      rs_s[nt][r] = v + res_b[i0 * 64 + 16 * w + q4 + r];
    }
  }
  RES_GEMM(i0, rs_s)
  // ===== ctx H staging (XT free: z readers done at last sync) =====
  STAGE_TAPS(t0)
  STAGE_COND(t0)
  __syncthreads();
  Z_GATE(i0)
  __syncthreads();
  #pragma unroll
  for (int nt = 0; nt < 4; ++nt) {
    const int tg = t0 + nt * 16 + l15;
    #pragma unroll
    for (int r = 0; r < 4; ++r)
      rs_h[nt][r] = rb[(size_t)(16 * w + q4 + r) * T_LEN + tg] +
                    res_b[i0 * 64 + 16 * w + q4 + r];
  }
  SKIP_GEMM(i0)
  RES_GEMM(i0, rs_h)
  // write layer-i1 taps from regs (XT free; CT home stays staged)
  #pragma unroll
  for (int nt = 0; nt < 4; ++nt) {
    us4v p1, p0;
    const bool ok = (t0s + nt * 16 + l15) >= 0;
    #pragma unroll
    for (int r = 0; r < 4; ++r) {
      p1[r] = f2bf(rs_h[nt][r]);
      p0[r] = ok ? f2bf(rs_s[nt][r]) : (ushort)0;
    }
    *reinterpret_cast<us4v*>(&XT[(nt * 16 + l15) * XSTR + 64 + 16 * w + q4]) = p1;
    *reinterpret_cast<us4v*>(&XT[(nt * 16 + l15) * XSTR + 16 * w + q4]) = p0;
  }
  __syncthreads();
  // ===== layer i1 at home =====
  Z_GATE(i1)
  __syncthreads();
  #pragma unroll
  for (int nt = 0; nt < 4; ++nt) {
    #pragma unroll
    for (int r = 0; r < 4; ++r)
      rs_s[nt][r] = rs_h[nt][r] + res_b[i1 * 64 + 16 * w + q4 + r];
  }
  SKIP_GEMM(i1)
  RES_GEMM(i1, rs_s)

  // ===== epilogue: skip RMW + res write =====
  {
    float* sg = skip + (size_t)b * 128 * T_LEN;
    float* ro = res_out + (size_t)b * 64 * T_LEN;
    #pragma unroll
    for (int nt = 0; nt < 4; ++nt) {
      const int tt = t0 + nt * 16 + l15;
      #pragma unroll
      for (int r = 0; r < 4; ++r) {
        sg[(size_t)(32 * w + q4 + r) * T_LEN + tt] += sk[nt][r];
        sg[(size_t)(32 * w + 16 + q4 + r) * T_LEN + tt] += sk[4 + nt][r];
        ro[(size_t)(16 * w + q4 + r) * T_LEN + tt] = rs_s[nt][r];
      }
    }
  }
#undef STAGE_TAPS
#undef STAGE_COND
#undef Z_GATE
#undef RES_GEMM
#undef SKIP_GEMM
}

// ---- post1: y1r = bf16(relu(p1_w @ relu(skip) + b)) ----
#define FSSTR 136
__global__ __launch_bounds__(256) void post1_mfma(
    const float* __restrict__ skip, const ushort* __restrict__ wp1,
    const float* __restrict__ p1b, ushort* __restrict__ y1r) {
  __shared__ ushort ST[64 * FSSTR];
  const int tid = threadIdx.x;
  const int lane = tid & 63;
  const int w = tid >> 6;
  const int t0 = blockIdx.x * 64;
  const int b = blockIdx.y;
  const float* sb = skip + (size_t)b * 128 * T_LEN;
  const int t = t0 + lane;
  for (int kc = 0; kc < 4; ++kc) {
    int k0 = w * 32 + kc * 8;
    us8v v;
    #pragma unroll
    for (int j = 0; j < 8; ++j)
      v[j] = f2bf(fmaxf(sb[(size_t)(k0 + j) * T_LEN + t], 0.f));
    *reinterpret_cast<us8v*>(&ST[lane * FSSTR + k0]) = v;
  }
  __syncthreads();
  const int q4 = 4 * (lane >> 4);
  facc acc[4][4];
  #pragma unroll
  for (int mi = 0; mi < 4; ++mi) {
    #pragma unroll
    for (int nt = 0; nt < 4; ++nt) {
      #pragma unroll
      for (int r = 0; r < 4; ++r)
        acc[mi][nt][r] = p1b[16 * (4 * w + mi) + q4 + r];
    }
  }
  const int lo = lane * 8;
  const int bofs = (lane & 15) * FSSTR + 8 * (lane >> 4);
  #pragma unroll
  for (int kt = 0; kt < 4; ++kt) {
    bfrag a[4];
    #pragma unroll
    for (int mi = 0; mi < 4; ++mi)
      a[mi] = ldfrag(wp1 + ((4 * w + mi) * 4 + kt) * 512 + lo);
    #pragma unroll
    for (int nt = 0; nt < 4; ++nt) {
      bfrag bb = ldfrag(&ST[nt * 16 * FSSTR + bofs + kt * 32]);
      #pragma unroll
      for (int mi = 0; mi < 4; ++mi) acc[mi][nt] = MFMA16(a[mi], bb, acc[mi][nt]);
    }
  }
  ushort* yb = y1r + (size_t)b * 256 * T_LEN;
  #pragma unroll
  for (int mi = 0; mi < 4; ++mi) {
    #pragma unroll
    for (int nt = 0; nt < 4; ++nt) {
      const int tt = t0 + nt * 16 + (lane & 15);
      #pragma unroll
      for (int r = 0; r < 4; ++r)
        yb[(size_t)(16 * (4 * w + mi) + q4 + r) * T_LEN + tt] =
            f2bf(fmaxf(acc[mi][nt][r], 0.f));
    }
  }
}

// ---- post2: out = p2_w @ y1r + b (fp32) ----
#define YSTR 264
__global__ __launch_bounds__(256) void post2_mfma(
    const ushort* __restrict__ y1r, const ushort* __restrict__ wp2,
    const float* __restrict__ p2b, float* __restrict__ out) {
  __shared__ ushort YT[64 * YSTR];
  const int tid = threadIdx.x;
  const int lane = tid & 63;
  const int w = tid >> 6;
  const int t0 = blockIdx.x * 64;
  const int b = blockIdx.y;
  const ushort* yb = y1r + (size_t)b * 256 * T_LEN;
  const int t = t0 + lane;
  for (int kc = 0; kc < 8; ++kc) {
    int k0 = w * 64 + kc * 8;
    us8v v;
    #pragma unroll
    for (int j = 0; j < 8; ++j) v[j] = yb[(size_t)(k0 + j) * T_LEN + t];
    *reinterpret_cast<us8v*>(&YT[lane * YSTR + k0]) = v;
  }
  __syncthreads();
  const int q4 = 4 * (lane >> 4);
  facc acc[4][4];
  #pragma unroll
  for (int mi = 0; mi < 4; ++mi) {
    #pragma unroll
    for (int nt = 0; nt < 4; ++nt) {
      #pragma unroll
      for (int r = 0; r < 4; ++r)
        acc[mi][nt][r] = p2b[16 * (4 * w + mi) + q4 + r];
    }
  }
  const int lo = lane * 8;
  const int bofs = (lane & 15) * YSTR + 8 * (lane >> 4);
  #pragma unroll
  for (int kt = 0; kt < 8; ++kt) {
    bfrag a[4];
    #pragma unroll
    for (int mi = 0; mi < 4; ++mi)
      a[mi] = ldfrag(wp2 + ((4 * w + mi) * 8 + kt) * 512 + lo);
    #pragma unroll
    for (int nt = 0; nt < 4; ++nt) {
      bfrag bb = ldfrag(&YT[nt * 16 * YSTR + bofs + kt * 32]);
      #pragma unroll
      for (int mi = 0; mi < 4; ++mi) acc[mi][nt] = MFMA16(a[mi], bb, acc[mi][nt]);
    }
  }
  float* ob = out + (size_t)b * 256 * T_LEN;
  #pragma unroll
  for (int mi = 0; mi < 4; ++mi) {
    #pragma unroll
    for (int nt = 0; nt < 4; ++nt) {
      const int tt = t0 + nt * 16 + (lane & 15);
      #pragma unroll
      for (int r = 0; r < 4; ++r)
        ob[(size_t)(16 * (4 * w + mi) + q4 + r) * T_LEN + tt] = acc[mi][nt][r];
    }
  }
}

extern "C" void kernel_launch(void* const* d_in, const int* in_sizes, int n_in,
                              void* d_out, int out_size, void* d_ws,
                              size_t ws_size, hipStream_t stream) {
  const float* x       = (const float*)d_in[0];
  const float* mels    = (const float*)d_in[1];
  const float* input_w = (const float*)d_in[2];
  const float* input_b = (const float*)d_in[3];
  const float* mel_w   = (const float*)d_in[4];
  const float* mel_b   = (const float*)d_in[5];
  const float* dil_w   = (const float*)d_in[6];
  const float* dil_b   = (const float*)d_in[7];
  const float* cond_w  = (const float*)d_in[8];
  const float* cond_b  = (const float*)d_in[9];
  const float* skip_w  = (const float*)d_in[10];
  const float* skip_b  = (const float*)d_in[11];
  const float* res_w   = (const float*)d_in[12];
  const float* res_b   = (const float*)d_in[13];
  const float* p1_w    = (const float*)d_in[14];
  const float* p1_b    = (const float*)d_in[15];
  const float* p2_w    = (const float*)d_in[16];
  const float* p2_b    = (const float*)d_in[17];

  char* ws = (char*)d_ws;
  float* res0   = (float*)(ws + RES0_OFF);
  float* res1   = (float*)(ws + RES1_OFF);
  ushort* condp = (ushort*)(ws + COND_OFF);
  ushort* wa    = (ushort*)(ws + WA_OFF);
  ushort* wsf   = (ushort*)(ws + WSF_OFF);
  ushort* wrf   = (ushort*)(ws + WRF_OFF);
  ushort* wp1   = (ushort*)(ws + WP1_OFF);
  ushort* wp2   = (ushort*)(ws + WP2_OFF);
  ushort* condA = (ushort*)(ws + CONDA_OFF);
  float* zbp    = (float*)(ws + ZB_OFF);
  float* skipg  = (float*)(ws + SKIPG_OFF);
  ushort* y1rp  = (ushort*)(ws + Y1R_OFF);
  float* out    = (float*)d_out;

  prep_kernel<<<2048, 256, 0, stream>>>(dil_w, cond_w, skip_w, res_w, p1_w,
                                        p2_w, mel_w, dil_b, cond_b, wa, wsf,
                                        wrf, wp1, wp2, condA, zbp);
  cond_mfma<<<dim3(64, BATCH, 2), 256, 0, stream>>>(mels, condA, mel_b, condp);
  init_res_kernel<<<(BATCH * 64 * T_LEN + 255) / 256, 256, 0, stream>>>(
      x, input_w, input_b, res0);
  hipMemsetAsync(skipg, 0, (size_t)BATCH * 128 * T_LEN * sizeof(float), stream);

  float* rin = res0;
  float* rout = res1;
  for (int p = 0; p < NPAIRS; ++p) {
    int i0 = 2 * p;
    int d0 = 1 << ((2 * p) % 10);
    wn_pair_kernel<<<dim3(NTILES, BATCH), 256, 0, stream>>>(
        rin, rout, condp, skipg, wa, wsf, wrf, zbp, skip_b, res_b, i0, d0);
    float* tmp = rin; rin = rout; rout = tmp;
  }

  post1_mfma<<<dim3(NTILES, BATCH), 256, 0, stream>>>(skipg, wp1, p1_b, y1rp);
  post2_mfma<<<dim3(NTILES, BATCH), 256, 0, stream>>>(y1rp, wp2, p2_b, out);
}

// Round 6
// 993.271 us; speedup vs baseline: 4.0297x; 1.2121x over previous
//
#include <hip/hip_runtime.h>
#include <math.h>

#define T_LEN 32512
#define NTILES 508
#define BATCH 2
#define NMEL 80
#define FRAMES 128
#define NBLK 30
#define NPAIRS 15
#define PAD 768
#define TP (T_LEN + PAD)  // 33280

typedef short bfrag __attribute__((ext_vector_type(8)));
typedef float facc __attribute__((ext_vector_type(4)));
typedef ushort us4v __attribute__((ext_vector_type(4)));
typedef ushort us8v __attribute__((ext_vector_type(8)));

#define MFMA16(a, b, c) __builtin_amdgcn_mfma_f32_16x16x32_bf16((a), (b), (c), 0, 0, 0)

// ---- workspace layout (byte offsets) ----
#define RESF_OFF   0u          // f32  [2buf][2b][TP][64] = 34,078,720
#define RESH_OFF   34078720u   // bf16 [2buf][2b][TP][64] = 17,039,360
#define CONDB_OFF  51118080u   // bf16 [2b][TP][96]       = 12,779,520
#define WA_OFF     63897600u   // bf16 30*56*512
#define WSF_OFF    65617920u   // bf16 30*16*512
#define WRF_OFF    66109440u   // bf16 30*8*512
#define WP1_OFF    66355200u   // bf16 64*512
#define WP2_OFF    66420736u   // bf16 128*512
#define ZB_OFF     66551808u   // f32 30*128
#define SBS_OFF    66567168u   // f32 128
#define SKIPG_OFF  66567680u   // f32 [2b][T][128] = 33,292,288
#define CONDA_OFF  SKIPG_OFF   // condA aliased (dead before skipg memset)
#define HB_OFF     99859968u   // bf16 h slots: [slot][2b][T][64]
#define SLOT_BYTES 8323072ull
#define SLOT_ELEMS 4161536ull
#define Y1R_OFF    0u          // bf16 [2b][256][T] aliases resf (dead after pairs)

static __device__ __forceinline__ ushort f2bf(float f) {
  union { float f; unsigned int u; } v;
  v.f = f;
  unsigned int r = (v.u + 0x7FFFu + ((v.u >> 16) & 1u)) >> 16;
  return (ushort)r;
}
static __device__ __forceinline__ float sigmoidf_(float x) {
  return 1.f / (1.f + __expf(-x));
}
static __device__ __forceinline__ float tanhf_(float x) {
  return 2.f / (1.f + __expf(-2.f * x)) - 1.f;
}
static __device__ __forceinline__ bfrag ldfrag(const ushort* p) {
  return *reinterpret_cast<const bfrag*>(p);
}

// ---- prep: weights -> MFMA A-fragments; condA; zb; sbs ----
__global__ __launch_bounds__(256) void prep_kernel(
    const float* __restrict__ dil_w, const float* __restrict__ cond_w,
    const float* __restrict__ skip_w, const float* __restrict__ res_w,
    const float* __restrict__ p1_w, const float* __restrict__ p2_w,
    const float* __restrict__ mel_w, const float* __restrict__ dil_b,
    const float* __restrict__ cond_b, const float* __restrict__ skip_b,
    ushort* __restrict__ wa, ushort* __restrict__ wsf, ushort* __restrict__ wrf,
    ushort* __restrict__ wp1, ushort* __restrict__ wp2,
    ushort* __restrict__ condA, float* __restrict__ zb,
    float* __restrict__ sbs) {
  int tid = blockIdx.x * blockDim.x + threadIdx.x;
  int stride = gridDim.x * blockDim.x;
  // W_all[layer][128 m][224 k]: k<64 tap0; k<128 tap1; k<208 cond(96-pad); else 0
  for (int idx = tid; idx < NBLK * 56 * 512; idx += stride) {
    int j = idx & 7, lane = (idx >> 3) & 63;
    int f = (idx >> 9) % 56, layer = idx / (56 * 512);
    int mt = f / 7, kt = f % 7;
    int m = 16 * mt + (lane & 15);
    int k = 32 * kt + 8 * (lane >> 4) + j;
    float v;
    if (k < 64)       v = dil_w[(((size_t)layer * 128 + m) * 64 + k) * 2 + 0];
    else if (k < 128) v = dil_w[(((size_t)layer * 128 + m) * 64 + (k - 64)) * 2 + 1];
    else if (k < 208) v = cond_w[((size_t)layer * 128 + m) * 80 + (k - 128)];
    else              v = 0.f;
    wa[idx] = f2bf(v);
  }
  for (int idx = tid; idx < NBLK * 16 * 512; idx += stride) {
    int j = idx & 7, lane = (idx >> 3) & 63;
    int f = (idx >> 9) & 15, layer = idx / (16 * 512);
    int mt = f >> 1, kt = f & 1;
    int m = 16 * mt + (lane & 15);
    int k = 32 * kt + 8 * (lane >> 4) + j;
    wsf[idx] = f2bf(skip_w[((size_t)layer * 128 + m) * 64 + k]);
  }
  for (int idx = tid; idx < NBLK * 8 * 512; idx += stride) {
    int j = idx & 7, lane = (idx >> 3) & 63;
    int f = (idx >> 9) & 7, layer = idx / (8 * 512);
    int mt = f >> 1, kt = f & 1;
    int m = 16 * mt + (lane & 15);
    int k = 32 * kt + 8 * (lane >> 4) + j;
    wrf[idx] = f2bf(res_w[((size_t)layer * 64 + m) * 64 + k]);
  }
  for (int idx = tid; idx < 64 * 512; idx += stride) {
    int j = idx & 7, lane = (idx >> 3) & 63;
    int f = idx >> 9;
    int mt = f >> 2, kt = f & 3;
    int m = 16 * mt + (lane & 15);
    int k = 32 * kt + 8 * (lane >> 4) + j;
    wp1[idx] = f2bf(p1_w[(size_t)m * 128 + k]);
  }
  for (int idx = tid; idx < 128 * 512; idx += stride) {
    int j = idx & 7, lane = (idx >> 3) & 63;
    int f = idx >> 9;
    int mt = f >> 3, kt = f & 7;
    int m = 16 * mt + (lane & 15);
    int k = 32 * kt + 8 * (lane >> 4) + j;
    wp2[idx] = f2bf(p2_w[(size_t)m * 256 + k]);
  }
  // condA[u][f=mt*5+kt][512]
  for (int idx = tid; idx < 25 * 512 * 256; idx += stride) {
    int u = idx & 255;
    int e = idx >> 8;
    int j = e & 7, lane = (e >> 3) & 63, f = e >> 9;
    int mt = f / 5, kt = f % 5;
    int m = 16 * mt + (lane & 15);
    int k = 32 * kt + 8 * (lane >> 4) + j;
    int ci = (k < 80) ? k : k - 80;
    int kk = (k < 80) ? (255 - u) : (511 - u);
    condA[((size_t)u * 25 + f) * 512 + lane * 8 + j] =
        f2bf(mel_w[((size_t)m * 80 + ci) * 512 + kk]);
  }
  for (int idx = tid; idx < NBLK * 128; idx += stride)
    zb[idx] = dil_b[idx] + cond_b[idx];
  for (int idx = tid; idx < 128; idx += stride) {
    float s = 0.f;
    for (int i2 = 0; i2 < NBLK; ++i2) s += skip_b[i2 * 128 + idx];
    sbs[idx] = s;
  }
}

// ---- mel upsample MFMA; writes cond t-major [b][TP][96] bf16 ----
#define BSTR 168
__global__ __launch_bounds__(256) void cond_mfma(
    const float* __restrict__ mels, const ushort* __restrict__ condA,
    const float* __restrict__ mel_b, ushort* __restrict__ condb) {
  __shared__ ushort BT[128 * BSTR];
  const int tid = threadIdx.x;
  const int lane = tid & 63;
  const int w = tid >> 6;
  const int b = blockIdx.y;
  const int half = blockIdx.z;
  const int u = blockIdx.x * 4 + w;
  const int q4 = 4 * (lane >> 4);
  const int l15 = lane & 15;
  const float* melb = mels + (size_t)b * NMEL * FRAMES;
  for (int idx = tid; idx < 160 * 128; idx += 256) {
    int M = idx & 127;
    int k = idx >> 7;
    int ci = (k < 80) ? k : k - 80;
    int Mp = M + ((k < 80) ? 0 : 1);
    float v = (Mp < 128) ? melb[(size_t)ci * FRAMES + Mp] : 0.f;
    BT[M * BSTR + k] = f2bf(v);
  }
  __syncthreads();
  facc acc[5][4];
  #pragma unroll
  for (int mt = 0; mt < 5; ++mt) {
    #pragma unroll
    for (int nt = 0; nt < 4; ++nt) {
      #pragma unroll
      for (int r = 0; r < 4; ++r) acc[mt][nt][r] = mel_b[16 * mt + q4 + r];
    }
  }
  const ushort* cA = condA + (size_t)u * 25 * 512 + lane * 8;
  const int bofs = l15 * BSTR + 8 * (lane >> 4);
  #pragma unroll
  for (int kt = 0; kt < 5; ++kt) {
    bfrag a[5];
    #pragma unroll
    for (int mt = 0; mt < 5; ++mt) a[mt] = ldfrag(cA + (mt * 5 + kt) * 512);
    #pragma unroll
    for (int nt = 0; nt < 4; ++nt) {
      bfrag bb = ldfrag(&BT[(half * 64 + nt * 16) * BSTR + bofs + kt * 32]);
      #pragma unroll
      for (int mt = 0; mt < 5; ++mt) acc[mt][nt] = MFMA16(a[mt], bb, acc[mt][nt]);
    }
  }
  ushort* cbp = condb + (size_t)b * TP * 96;
  #pragma unroll
  for (int mt = 0; mt < 5; ++mt) {
    #pragma unroll
    for (int nt = 0; nt < 4; ++nt) {
      const int M = half * 64 + nt * 16 + l15;
      if (M < 127) {
        us4v p;
        #pragma unroll
        for (int r = 0; r < 4; ++r) p[r] = f2bf(acc[mt][nt][r]);
        const int t = M * 256 + u;
        *reinterpret_cast<us4v*>(&cbp[(size_t)(t + PAD) * 96 + 16 * mt + q4]) = p;
      }
    }
  }
}

// ---- init: res_0 fp32 + bf16, t-major rows [PAD, PAD+T) ----
__global__ __launch_bounds__(256) void init_res_kernel(
    const float* __restrict__ x, const float* __restrict__ iw,
    const float* __restrict__ ib, float* __restrict__ resf0,
    ushort* __restrict__ resh0) {
  int idx = blockIdx.x * blockDim.x + threadIdx.x;
  if (idx >= BATCH * T_LEN * 64) return;
  int c = idx & 63;
  int t = (idx >> 6) % T_LEN;
  int b = idx / (64 * T_LEN);
  float v = x[(size_t)b * T_LEN + t] * iw[c] + ib[c];
  size_t o = (size_t)b * TP * 64 + (size_t)(t + PAD) * 64 + c;
  resf0[o] = v;
  resh0[o] = f2bf(v);
}

// ============ pair kernel: layers (i0,i0+1), global bf16 B-fragments ============
template <int DEFER>
__global__ __launch_bounds__(256, 4) void wn_pair_kernel(
    const float* __restrict__ resf_in, float* __restrict__ resf_out,
    const ushort* __restrict__ resh_in, ushort* __restrict__ resh_out,
    const ushort* __restrict__ condb, const ushort* __restrict__ wa,
    const ushort* __restrict__ wsf, const ushort* __restrict__ wrf,
    const float* __restrict__ zb, const float* __restrict__ res_b,
    const float* __restrict__ skip_b, float* __restrict__ skipg,
    ushort* __restrict__ hb0, ushort* __restrict__ hb1, int i0, int d0) {
  __shared__ ushort HT[64 * 72];
  __shared__ ushort RTs[64 * 72];
  __shared__ ushort RTh[64 * 72];
  const int i1 = i0 + 1;
  const int d1 = 2 * d0;
  const int tid = threadIdx.x;
  const int lane = tid & 63;
  const int w = tid >> 6;
  const int l15 = lane & 15;
  const int q4 = 4 * (lane >> 4);
  const int colq = 8 * (lane >> 4);
  // bijective XCD swizzle (508 = 8*63+4)
  const int orig = blockIdx.x;
  const int xcd = orig & 7;
  const int loc = orig >> 3;
  const int tile = (xcd < 4 ? xcd * 64 : 256 + (xcd - 4) * 63) + loc;
  const int t0 = tile * 64;
  const int t0s = t0 - d1;
  const int b = blockIdx.y;

  const float* rfi = resf_in + (size_t)b * TP * 64;
  float* rfo = resf_out + (size_t)b * TP * 64;
  const ushort* rhi = resh_in + (size_t)b * TP * 64;
  ushort* rho = resh_out + (size_t)b * TP * 64;
  const ushort* cbp = condb + (size_t)b * TP * 96;
  const int bofs_h = l15 * 72 + colq;

  facc rs_s[4], rs_h[4], sk[8];
  facc accF[4], accG[4];
  if constexpr (!DEFER) {
    #pragma unroll
    for (int j = 0; j < 8; ++j) {
      const int ch = 32 * w + 16 * (j >> 2) + q4;
      facc s0 = *(const facc*)(skip_b + i0 * 128 + ch);
      facc s1 = *(const facc*)(skip_b + i1 * 128 + ch);
      sk[j] = s0 + s1;
    }
  }

#define ZG_INITB(LAYER)                                                       \
  _Pragma("unroll")                                                           \
  for (int nt = 0; nt < 4; ++nt) {                                            \
    accF[nt] = *(const facc*)(zb + (LAYER) * 128 + 16 * w + q4);              \
    accG[nt] = *(const facc*)(zb + (LAYER) * 128 + 64 + 16 * w + q4);         \
  }

#define ZG_GLOBAL(LAYER, TB)                                                  \
  {                                                                           \
    ZG_INITB(LAYER)                                                           \
    const ushort* wal = wa + (size_t)(LAYER) * 56 * 512 + lane * 8;           \
    const ushort* bp0[4];                                                     \
    const ushort* bp1[4];                                                     \
    const ushort* bpc[4];                                                     \
    _Pragma("unroll")                                                         \
    for (int nt = 0; nt < 4; ++nt) {                                          \
      const int tg = (TB) + nt * 16 + l15;                                    \
      bp0[nt] = rhi + (size_t)(tg - d0 + PAD) * 64 + colq;                    \
      bp1[nt] = rhi + (size_t)(tg + PAD) * 64 + colq;                         \
      bpc[nt] = cbp + (size_t)(tg + PAD) * 96 + colq;                         \
    }                                                                         \
    _Pragma("unroll")                                                         \
    for (int kt = 0; kt < 7; ++kt) {                                          \
      bfrag aF = ldfrag(wal + (w * 7 + kt) * 512);                            \
      bfrag aG = ldfrag(wal + ((w + 4) * 7 + kt) * 512);                      \
      _Pragma("unroll")                                                       \
      for (int nt = 0; nt < 4; ++nt) {                                        \
        bfrag bb = (kt < 2)   ? ldfrag(bp0[nt] + kt * 32)                     \
                   : (kt < 4) ? ldfrag(bp1[nt] + (kt - 2) * 32)               \
                              : ldfrag(bpc[nt] + (kt - 4) * 32);              \
        accF[nt] = MFMA16(aF, bb, accF[nt]);                                  \
        accG[nt] = MFMA16(aG, bb, accG[nt]);                                  \
      }                                                                       \
    }                                                                         \
  }

#define ZG_LDS(LAYER)                                                        \
  {                                                                           \
    ZG_INITB(LAYER)                                                           \
    const ushort* wal = wa + (size_t)(LAYER) * 56 * 512 + lane * 8;           \
    const ushort* bpc[4];                                                     \
    _Pragma("unroll")                                                         \
    for (int nt = 0; nt < 4; ++nt)                                            \
      bpc[nt] = cbp + (size_t)(t0 + nt * 16 + l15 + PAD) * 96 + colq;         \
    _Pragma("unroll")                                                         \
    for (int kt = 0; kt < 7; ++kt) {                                          \
      bfrag aF = ldfrag(wal + (w * 7 + kt) * 512);                            \
      bfrag aG = ldfrag(wal + ((w + 4) * 7 + kt) * 512);                      \
      _Pragma("unroll")                                                       \
      for (int nt = 0; nt < 4; ++nt) {                                        \
        bfrag bb = (kt < 2)                                                   \
            ? ldfrag(&RTs[(nt * 16 + l15) * 72 + kt * 32 + colq])             \
            : (kt < 4)                                                        \
                ? ldfrag(&RTh[(nt * 16 + l15) * 72 + (kt - 2) * 32 + colq])   \
                : ldfrag(bpc[nt] + (kt - 4) * 32);                            \
        accF[nt] = MFMA16(aF, bb, accF[nt]);                                  \
        accG[nt] = MFMA16(aG, bb, accG[nt]);                                  \
      }                                                                       \
    }                                                                         \
  }

#define GATE(HBPTR, DOHB)                                                     \
  {                                                                           \
    _Pragma("unroll")                                                         \
    for (int nt = 0; nt < 4; ++nt) {                                          \
      us4v p;                                                                 \
      _Pragma("unroll")                                                       \
      for (int r = 0; r < 4; ++r)                                             \
        p[r] = f2bf(tanhf_(accF[nt][r]) * sigmoidf_(accG[nt][r]));            \
      *reinterpret_cast<us4v*>(&HT[(nt * 16 + l15) * 72 + 16 * w + q4]) = p;  \
      if (DOHB)                                                               \
        *reinterpret_cast<us4v*>((HBPTR) + (size_t)b * T_LEN * 64 +           \
                                 (size_t)(t0 + nt * 16 + l15) * 64 +          \
                                 16 * w + q4) = p;                            \
    }                                                                         \
  }

#define RES_GEMM(LAYER, RS)                                                   \
  {                                                                           \
    const ushort* wrl = wrf + (size_t)(LAYER) * 8 * 512 + lane * 8;           \
    _Pragma("unroll")                                                         \
    for (int kt = 0; kt < 2; ++kt) {                                          \
      bfrag ar = ldfrag(wrl + (w * 2 + kt) * 512);                            \
      _Pragma("unroll")                                                       \
      for (int nt = 0; nt < 4; ++nt) {                                        \
        bfrag bb = ldfrag(&HT[nt * 16 * 72 + bofs_h + kt * 32]);              \
        RS[nt] = MFMA16(ar, bb, RS[nt]);                                      \
      }                                                                       \
    }                                                                         \
  }

#define SKIP_GEMM(LAYER)                                                      \
  {                                                                           \
    const ushort* wsl = wsf + (size_t)(LAYER) * 16 * 512 + lane * 8;          \
    _Pragma("unroll")                                                         \
    for (int kt = 0; kt < 2; ++kt) {                                          \
      bfrag a0 = ldfrag(wsl + ((2 * w) * 2 + kt) * 512);                      \
      bfrag a1 = ldfrag(wsl + ((2 * w + 1) * 2 + kt) * 512);                  \
      _Pragma("unroll")                                                       \
      for (int nt = 0; nt < 4; ++nt) {                                        \
        bfrag bb = ldfrag(&HT[nt * 16 * 72 + bofs_h + kt * 32]);              \
        sk[nt] = MFMA16(a0, bb, sk[nt]);                                      \
        sk[4 + nt] = MFMA16(a1, bb, sk[4 + nt]);                              \
      }                                                                       \
    }                                                                         \
  }

  // ===== ctx S: layer i0 @ shifted tile =====
  ZG_GLOBAL(i0, t0s);
  GATE(hb0, 0);
  __syncthreads();
  #pragma unroll
  for (int nt = 0; nt < 4; ++nt) {
    const int tg = t0s + nt * 16 + l15;
    facc v = *(const facc*)(rfi + (size_t)(tg + PAD) * 64 + 16 * w + q4);
    facc rbv = *(const facc*)(res_b + i0 * 64 + 16 * w + q4);
    rs_s[nt] = v + rbv;
  }
  RES_GEMM(i0, rs_s);
  #pragma unroll
  for (int nt = 0; nt < 4; ++nt) {
    const bool ok = (t0s + nt * 16 + l15) >= 0;
    us4v p;
    #pragma unroll
    for (int r = 0; r < 4; ++r) p[r] = ok ? f2bf(rs_s[nt][r]) : (ushort)0;
    *reinterpret_cast<us4v*>(&RTs[(nt * 16 + l15) * 72 + 16 * w + q4]) = p;
  }
  __syncthreads();
  // ===== ctx H: layer i0 @ home =====
  ZG_GLOBAL(i0, t0);
  GATE(hb0, DEFER);
  __syncthreads();
  #pragma unroll
  for (int nt = 0; nt < 4; ++nt) {
    const int tg = t0 + nt * 16 + l15;
    facc v = *(const facc*)(rfi + (size_t)(tg + PAD) * 64 + 16 * w + q4);
    facc rbv = *(const facc*)(res_b + i0 * 64 + 16 * w + q4);
    rs_h[nt] = v + rbv;
  }
  if constexpr (!DEFER) { SKIP_GEMM(i0); }
  RES_GEMM(i0, rs_h);
  #pragma unroll
  for (int nt = 0; nt < 4; ++nt) {
    us4v p;
    #pragma unroll
    for (int r = 0; r < 4; ++r) p[r] = f2bf(rs_h[nt][r]);
    *reinterpret_cast<us4v*>(&RTh[(nt * 16 + l15) * 72 + 16 * w + q4]) = p;
  }
  __syncthreads();
  // ===== layer i1 @ home (taps from RTs/RTh) =====
  ZG_LDS(i1);
  GATE(hb1, DEFER);
  __syncthreads();
  #pragma unroll
  for (int nt = 0; nt < 4; ++nt) {
    facc rbv = *(const facc*)(res_b + i1 * 64 + 16 * w + q4);
    rs_s[nt] = rs_h[nt] + rbv;
  }
  if constexpr (!DEFER) { SKIP_GEMM(i1); }
  RES_GEMM(i1, rs_s);
  // ===== epilogue =====
  #pragma unroll
  for (int nt = 0; nt < 4; ++nt) {
    const int tg = t0 + nt * 16 + l15;
    *(facc*)(rfo + (size_t)(tg + PAD) * 64 + 16 * w + q4) = rs_s[nt];
    us4v p;
    #pragma unroll
    for (int r = 0; r < 4; ++r) p[r] = f2bf(rs_s[nt][r]);
    *reinterpret_cast<us4v*>(rho + (size_t)(tg + PAD) * 64 + 16 * w + q4) = p;
  }
  if constexpr (!DEFER) {
    float* sg = skipg + (size_t)b * T_LEN * 128;
    #pragma unroll
    for (int nt = 0; nt < 4; ++nt) {
      const int tg = t0 + nt * 16 + l15;
      facc* p0 = (facc*)(sg + (size_t)tg * 128 + 32 * w + q4);
      facc* p1 = (facc*)(sg + (size_t)tg * 128 + 32 * w + 16 + q4);
      *p0 = *p0 + sk[nt];
      *p1 = *p1 + sk[4 + nt];
    }
  }
#undef ZG_INITB
#undef ZG_GLOBAL
#undef ZG_LDS
#undef GATE
#undef RES_GEMM
#undef SKIP_GEMM
}

// ---- skip_accum: skipg += sum_l Ws_l @ h_l (MFMA, fp32 accum) ----
__global__ __launch_bounds__(256) void skip_accum(
    const ushort* __restrict__ hb, const ushort* __restrict__ wsf,
    float* __restrict__ skipg, int base, int nl) {
  const int tid = threadIdx.x;
  const int lane = tid & 63;
  const int w = tid >> 6;
  const int l15 = lane & 15;
  const int q4 = 4 * (lane >> 4);
  const int colq = 8 * (lane >> 4);
  const int t0 = blockIdx.x * 64;
  const int b = blockIdx.y;
  float* sg = skipg + (size_t)b * T_LEN * 128;
  facc a0[4], a1[4];
  #pragma unroll
  for (int nt = 0; nt < 4; ++nt) {
    const int tg = t0 + nt * 16 + l15;
    a0[nt] = *(const facc*)(sg + (size_t)tg * 128 + 32 * w + q4);
    a1[nt] = *(const facc*)(sg + (size_t)tg * 128 + 32 * w + 16 + q4);
  }
  for (int l = 0; l < nl; ++l) {
    const int layer = base + l;
    const ushort* hp = hb + (size_t)l * SLOT_ELEMS + (size_t)b * T_LEN * 64;
    const ushort* wsl = wsf + (size_t)layer * 16 * 512 + lane * 8;
    #pragma unroll
    for (int kt = 0; kt < 2; ++kt) {
      bfrag f0 = ldfrag(wsl + ((2 * w) * 2 + kt) * 512);
      bfrag f1 = ldfrag(wsl + ((2 * w + 1) * 2 + kt) * 512);
      #pragma unroll
      for (int nt = 0; nt < 4; ++nt) {
        bfrag bb =
            ldfrag(hp + (size_t)(t0 + nt * 16 + l15) * 64 + kt * 32 + colq);
        a0[nt] = MFMA16(f0, bb, a0[nt]);
        a1[nt] = MFMA16(f1, bb, a1[nt]);
      }
    }
  }
  #pragma unroll
  for (int nt = 0; nt < 4; ++nt) {
    const int tg = t0 + nt * 16 + l15;
    *(facc*)(sg + (size_t)tg * 128 + 32 * w + q4) = a0[nt];
    *(facc*)(sg + (size_t)tg * 128 + 32 * w + 16 + q4) = a1[nt];
  }
}

// ---- post1: y1r = bf16(relu(P1 @ relu(skipg + sbs) + b)) ----
#define FSSTR 136
__global__ __launch_bounds__(256) void post1_mfma(
    const float* __restrict__ skipg, const float* __restrict__ sbs,
    const ushort* __restrict__ wp1, const float* __restrict__ p1b,
    ushort* __restrict__ y1r) {
  __shared__ ushort ST[64 * FSSTR];
  const int tid = threadIdx.x;
  const int lane = tid & 63;
  const int w = tid >> 6;
  const int t0 = blockIdx.x * 64;
  const int b = blockIdx.y;
  {
    const int t = tid & 63;
    const int kc = tid >> 6;
    const float* sp =
        skipg + (size_t)b * T_LEN * 128 + (size_t)(t0 + t) * 128 + kc * 32;
    #pragma unroll
    for (int j = 0; j < 8; ++j) {
      facc v = *(const facc*)(sp + j * 4);
      facc s = *(const facc*)(sbs + kc * 32 + j * 4);
      us4v o;
      #pragma unroll
      for (int r = 0; r < 4; ++r) o[r] = f2bf(fmaxf(v[r] + s[r], 0.f));
      *reinterpret_cast<us4v*>(&ST[t * FSSTR + kc * 32 + j * 4]) = o;
    }
  }
  __syncthreads();
  const int q4 = 4 * (lane >> 4);
  facc acc[4][4];
  #pragma unroll
  for (int mi = 0; mi < 4; ++mi) {
    #pragma unroll
    for (int nt = 0; nt < 4; ++nt) {
      #pragma unroll
      for (int r = 0; r < 4; ++r)
        acc[mi][nt][r] = p1b[16 * (4 * w + mi) + q4 + r];
    }
  }
  const int lo = lane * 8;
  const int bofs = (lane & 15) * FSSTR + 8 * (lane >> 4);
  #pragma unroll
  for (int kt = 0; kt < 4; ++kt) {
    bfrag a[4];
    #pragma unroll
    for (int mi = 0; mi < 4; ++mi)
      a[mi] = ldfrag(wp1 + ((4 * w + mi) * 4 + kt) * 512 + lo);
    #pragma unroll
    for (int nt = 0; nt < 4; ++nt) {
      bfrag bb = ldfrag(&ST[nt * 16 * FSSTR + bofs + kt * 32]);
      #pragma unroll
      for (int mi = 0; mi < 4; ++mi) acc[mi][nt] = MFMA16(a[mi], bb, acc[mi][nt]);
    }
  }
  ushort* yb = y1r + (size_t)b * 256 * T_LEN;
  #pragma unroll
  for (int mi = 0; mi < 4; ++mi) {
    #pragma unroll
    for (int nt = 0; nt < 4; ++nt) {
      const int tt = t0 + nt * 16 + (lane & 15);
      #pragma unroll
      for (int r = 0; r < 4; ++r)
        yb[(size_t)(16 * (4 * w + mi) + q4 + r) * T_LEN + tt] =
            f2bf(fmaxf(acc[mi][nt][r], 0.f));
    }
  }
}

// ---- post2: out = p2_w @ y1r + b (fp32) ----
#define YSTR 264
__global__ __launch_bounds__(256) void post2_mfma(
    const ushort* __restrict__ y1r, const ushort* __restrict__ wp2,
    const float* __restrict__ p2b, float* __restrict__ out) {
  __shared__ ushort YT[64 * YSTR];
  const int tid = threadIdx.x;
  const int lane = tid & 63;
  const int w = tid >> 6;
  const int t0 = blockIdx.x * 64;
  const int b = blockIdx.y;
  const ushort* yb = y1r + (size_t)b * 256 * T_LEN;
  const int t = t0 + lane;
  for (int kc = 0; kc < 8; ++kc) {
    int k0 = w * 64 + kc * 8;
    us8v v;
    #pragma unroll
    for (int j = 0; j < 8; ++j) v[j] = yb[(size_t)(k0 + j) * T_LEN + t];
    *reinterpret_cast<us8v*>(&YT[lane * YSTR + k0]) = v;
  }
  __syncthreads();
  const int q4 = 4 * (lane >> 4);
  facc acc[4][4];
  #pragma unroll
  for (int mi = 0; mi < 4; ++mi) {
    #pragma unroll
    for (int nt = 0; nt < 4; ++nt) {
      #pragma unroll
      for (int r = 0; r < 4; ++r)
        acc[mi][nt][r] = p2b[16 * (4 * w + mi) + q4 + r];
    }
  }
  const int lo = lane * 8;
  const int bofs = (lane & 15) * YSTR + 8 * (lane >> 4);
  #pragma unroll
  for (int kt = 0; kt < 8; ++kt) {
    bfrag a[4];
    #pragma unroll
    for (int mi = 0; mi < 4; ++mi)
      a[mi] = ldfrag(wp2 + ((4 * w + mi) * 8 + kt) * 512 + lo);
    #pragma unroll
    for (int nt = 0; nt < 4; ++nt) {
      bfrag bb = ldfrag(&YT[nt * 16 * YSTR + bofs + kt * 32]);
      #pragma unroll
      for (int mi = 0; mi < 4; ++mi) acc[mi][nt] = MFMA16(a[mi], bb, acc[mi][nt]);
    }
  }
  float* ob = out + (size_t)b * 256 * T_LEN;
  #pragma unroll
  for (int mi = 0; mi < 4; ++mi) {
    #pragma unroll
    for (int nt = 0; nt < 4; ++nt) {
      const int tt = t0 + nt * 16 + (lane & 15);
      #pragma unroll
      for (int r = 0; r < 4; ++r)
        ob[(size_t)(16 * (4 * w + mi) + q4 + r) * T_LEN + tt] = acc[mi][nt][r];
    }
  }
}

extern "C" void kernel_launch(void* const* d_in, const int* in_sizes, int n_in,
                              void* d_out, int out_size, void* d_ws,
                              size_t ws_size, hipStream_t stream) {
  const float* x       = (const float*)d_in[0];
  const float* mels    = (const float*)d_in[1];
  const float* input_w = (const float*)d_in[2];
  const float* input_b = (const float*)d_in[3];
  const float* mel_w   = (const float*)d_in[4];
  const float* mel_b   = (const float*)d_in[5];
  const float* dil_w   = (const float*)d_in[6];
  const float* dil_b   = (const float*)d_in[7];
  const float* cond_w  = (const float*)d_in[8];
  const float* cond_b  = (const float*)d_in[9];
  const float* skip_w  = (const float*)d_in[10];
  const float* skip_b  = (const float*)d_in[11];
  const float* res_w   = (const float*)d_in[12];
  const float* res_b   = (const float*)d_in[13];
  const float* p1_w    = (const float*)d_in[14];
  const float* p1_b    = (const float*)d_in[15];
  const float* p2_w    = (const float*)d_in[16];
  const float* p2_b    = (const float*)d_in[17];

  char* ws = (char*)d_ws;
  float* rfA    = (float*)(ws + RESF_OFF);
  float* rfB    = rfA + (size_t)2 * TP * 64;
  ushort* rhA   = (ushort*)(ws + RESH_OFF);
  ushort* rhB   = rhA + (size_t)2 * TP * 64;
  ushort* condb = (ushort*)(ws + CONDB_OFF);
  ushort* wa    = (ushort*)(ws + WA_OFF);
  ushort* wsf   = (ushort*)(ws + WSF_OFF);
  ushort* wrf   = (ushort*)(ws + WRF_OFF);
  ushort* wp1   = (ushort*)(ws + WP1_OFF);
  ushort* wp2   = (ushort*)(ws + WP2_OFF);
  float* zbp    = (float*)(ws + ZB_OFF);
  float* sbsp   = (float*)(ws + SBS_OFF);
  float* skipg  = (float*)(ws + SKIPG_OFF);
  ushort* condA = (ushort*)(ws + CONDA_OFF);
  ushort* hbuf  = (ushort*)(ws + HB_OFF);
  ushort* y1rp  = (ushort*)(ws + Y1R_OFF);
  float* out    = (float*)d_out;

  // group size G from ws_size (h-deferral); G=0 -> in-kernel skip RMW
  int G = 0;
  if (ws_size >= (size_t)HB_OFF + 30ull * SLOT_BYTES) {
    G = 15;
  } else if (ws_size >= (size_t)HB_OFF + 2ull * SLOT_BYTES) {
    G = (int)((ws_size - HB_OFF) / (2ull * SLOT_BYTES));
    if (G > 15) G = 15;
  }
  const bool defer = (G >= 1);

  // zero prefixes (causal padding) + cond buffer pads
  for (int k = 0; k < 2; ++k)
    for (int b = 0; b < 2; ++b) {
      hipMemsetAsync((char*)(k == 0 ? rfA : rfB) + (size_t)b * TP * 64 * 4, 0,
                     (size_t)PAD * 64 * 4, stream);
      hipMemsetAsync((char*)(k == 0 ? rhA : rhB) + (size_t)b * TP * 64 * 2, 0,
                     (size_t)PAD * 64 * 2, stream);
    }
  hipMemsetAsync(condb, 0, (size_t)2 * TP * 96 * 2, stream);

  prep_kernel<<<2048, 256, 0, stream>>>(dil_w, cond_w, skip_w, res_w, p1_w,
                                        p2_w, mel_w, dil_b, cond_b, skip_b, wa,
                                        wsf, wrf, wp1, wp2, condA, zbp, sbsp);
  cond_mfma<<<dim3(64, BATCH, 2), 256, 0, stream>>>(mels, condA, mel_b, condb);
  // skipg memset AFTER cond_mfma (condA aliases skipg region)
  hipMemsetAsync(skipg, 0, (size_t)2 * T_LEN * 128 * 4, stream);
  init_res_kernel<<<(BATCH * T_LEN * 64 + 255) / 256, 256, 0, stream>>>(
      x, input_w, input_b, rfA, rhA);

  float* rfi = rfA;
  float* rfo = rfB;
  ushort* rhi = rhA;
  ushort* rho = rhB;
  int groupStart = 0;
  for (int p = 0; p < NPAIRS; ++p) {
    int i0 = 2 * p;
    int d0 = 1 << (i0 % 10);
    if (defer) {
      ushort* h0 = hbuf + (size_t)(2 * (p - groupStart)) * SLOT_ELEMS;
      wn_pair_kernel<1><<<dim3(NTILES, BATCH), 256, 0, stream>>>(
          rfi, rfo, rhi, rho, condb, wa, wsf, wrf, zbp, res_b, skip_b, skipg,
          h0, h0 + SLOT_ELEMS, i0, d0);
      if (p - groupStart + 1 == G || p == NPAIRS - 1) {
        skip_accum<<<dim3(NTILES, BATCH), 256, 0, stream>>>(
            hbuf, wsf, skipg, 2 * groupStart, 2 * (p - groupStart + 1));
        groupStart = p + 1;
      }
    } else {
      wn_pair_kernel<0><<<dim3(NTILES, BATCH), 256, 0, stream>>>(
          rfi, rfo, rhi, rho, condb, wa, wsf, wrf, zbp, res_b, skip_b, skipg,
          nullptr, nullptr, i0, d0);
    }
    float* tf = rfi; rfi = rfo; rfo = tf;
    ushort* th = rhi; rhi = rho; rho = th;
  }

  post1_mfma<<<dim3(NTILES, BATCH), 256, 0, stream>>>(skipg, sbsp, wp1, p1_b,
                                                      y1rp);
  post2_mfma<<<dim3(NTILES, BATCH), 256, 0, stream>>>(y1rp, wp2, p2_b, out);
}

// Round 7
// 901.716 us; speedup vs baseline: 4.4389x; 1.1015x over previous
//
#include <hip/hip_runtime.h>
#include <math.h>

#define T_LEN 32512
#define NTILES 508
#define BATCH 2
#define NMEL 80
#define FRAMES 128
#define NBLK 30
#define NPAIRS 15
#define PAD 768
#define TP (T_LEN + PAD)  // 33280

typedef short bfrag __attribute__((ext_vector_type(8)));
typedef float facc __attribute__((ext_vector_type(4)));
typedef ushort us4v __attribute__((ext_vector_type(4)));
typedef ushort us8v __attribute__((ext_vector_type(8)));

#define MFMA16(a, b, c) __builtin_amdgcn_mfma_f32_16x16x32_bf16((a), (b), (c), 0, 0, 0)

// ---- workspace layout (byte offsets) ----
#define RESF_OFF   0u          // f32  [2buf][2b][TP][64] = 34,078,720
#define RESH_OFF   34078720u   // bf16 [2buf][2b][TP][64] = 17,039,360
#define CONDB_OFF  51118080u   // bf16 [2b][TP][96]       = 12,779,520
#define WA_OFF     63897600u   // bf16 30*56*512
#define WSF_OFF    65617920u   // bf16 30*16*512
#define WRF_OFF    66109440u   // bf16 30*8*512
#define WP1_OFF    66355200u   // bf16 64*512
#define WP2_OFF    66420736u   // bf16 128*512
#define ZB_OFF     66551808u   // f32 30*128
#define SBS_OFF    66567168u   // f32 128
#define SKIPG_OFF  66567680u   // f32 [2b][T][128] = 33,292,288
#define CONDA_OFF  SKIPG_OFF   // condA aliased (dead before first skip_accum)
#define HB_OFF     99859968u   // bf16 h slots: [slot][2b][T][64]
#define SLOT_BYTES 8323072ull
#define SLOT_ELEMS 4161536ull
#define Y1R_OFF    0u          // bf16 [2b][256][T] aliases resf (dead after pairs)

static __device__ __forceinline__ ushort f2bf(float f) {
  union { float f; unsigned int u; } v;
  v.f = f;
  unsigned int r = (v.u + 0x7FFFu + ((v.u >> 16) & 1u)) >> 16;
  return (ushort)r;
}
static __device__ __forceinline__ float bf2f(ushort h) {
  union { unsigned int u; float f; } v;
  v.u = ((unsigned int)h) << 16;
  return v.f;
}
static __device__ __forceinline__ float sigmoidf_(float x) {
  return 1.f / (1.f + __expf(-x));
}
static __device__ __forceinline__ float tanhf_(float x) {
  return 2.f / (1.f + __expf(-2.f * x)) - 1.f;
}
static __device__ __forceinline__ bfrag ldfrag(const ushort* p) {
  return *reinterpret_cast<const bfrag*>(p);
}
static __device__ __forceinline__ void gload_lds16(const void* g, void* l) {
  __builtin_amdgcn_global_load_lds(
      (const __attribute__((address_space(1))) unsigned int*)g,
      (__attribute__((address_space(3))) unsigned int*)l, 16, 0, 0);
}

// ---- prep: weights -> MFMA A-fragments; condA; zb; sbs ----
__global__ __launch_bounds__(256) void prep_kernel(
    const float* __restrict__ dil_w, const float* __restrict__ cond_w,
    const float* __restrict__ skip_w, const float* __restrict__ res_w,
    const float* __restrict__ p1_w, const float* __restrict__ p2_w,
    const float* __restrict__ mel_w, const float* __restrict__ dil_b,
    const float* __restrict__ cond_b, const float* __restrict__ skip_b,
    ushort* __restrict__ wa, ushort* __restrict__ wsf, ushort* __restrict__ wrf,
    ushort* __restrict__ wp1, ushort* __restrict__ wp2,
    ushort* __restrict__ condA, float* __restrict__ zb,
    float* __restrict__ sbs) {
  int tid = blockIdx.x * blockDim.x + threadIdx.x;
  int stride = gridDim.x * blockDim.x;
  // W_all[layer][128 m][224 k]: k<64 tap0; k<128 tap1; k<208 cond(96-pad); else 0
  for (int idx = tid; idx < NBLK * 56 * 512; idx += stride) {
    int j = idx & 7, lane = (idx >> 3) & 63;
    int f = (idx >> 9) % 56, layer = idx / (56 * 512);
    int mt = f / 7, kt = f % 7;
    int m = 16 * mt + (lane & 15);
    int k = 32 * kt + 8 * (lane >> 4) + j;
    float v;
    if (k < 64)       v = dil_w[(((size_t)layer * 128 + m) * 64 + k) * 2 + 0];
    else if (k < 128) v = dil_w[(((size_t)layer * 128 + m) * 64 + (k - 64)) * 2 + 1];
    else if (k < 208) v = cond_w[((size_t)layer * 128 + m) * 80 + (k - 128)];
    else              v = 0.f;
    wa[idx] = f2bf(v);
  }
  for (int idx = tid; idx < NBLK * 16 * 512; idx += stride) {
    int j = idx & 7, lane = (idx >> 3) & 63;
    int f = (idx >> 9) & 15, layer = idx / (16 * 512);
    int mt = f >> 1, kt = f & 1;
    int m = 16 * mt + (lane & 15);
    int k = 32 * kt + 8 * (lane >> 4) + j;
    wsf[idx] = f2bf(skip_w[((size_t)layer * 128 + m) * 64 + k]);
  }
  for (int idx = tid; idx < NBLK * 8 * 512; idx += stride) {
    int j = idx & 7, lane = (idx >> 3) & 63;
    int f = (idx >> 9) & 7, layer = idx / (8 * 512);
    int mt = f >> 1, kt = f & 1;
    int m = 16 * mt + (lane & 15);
    int k = 32 * kt + 8 * (lane >> 4) + j;
    wrf[idx] = f2bf(res_w[((size_t)layer * 64 + m) * 64 + k]);
  }
  for (int idx = tid; idx < 64 * 512; idx += stride) {
    int j = idx & 7, lane = (idx >> 3) & 63;
    int f = idx >> 9;
    int mt = f >> 2, kt = f & 3;
    int m = 16 * mt + (lane & 15);
    int k = 32 * kt + 8 * (lane >> 4) + j;
    wp1[idx] = f2bf(p1_w[(size_t)m * 128 + k]);
  }
  for (int idx = tid; idx < 128 * 512; idx += stride) {
    int j = idx & 7, lane = (idx >> 3) & 63;
    int f = idx >> 9;
    int mt = f >> 3, kt = f & 7;
    int m = 16 * mt + (lane & 15);
    int k = 32 * kt + 8 * (lane >> 4) + j;
    wp2[idx] = f2bf(p2_w[(size_t)m * 256 + k]);
  }
  // condA[u][f=mt*5+kt][512] -- linear index = write-contiguous
  for (int idx = tid; idx < 25 * 512 * 256; idx += stride) {
    int q = idx & 511;
    int f = (idx >> 9) % 25;
    int u = idx / (25 * 512);
    int j = q & 7, lane = q >> 3;
    int mt = f / 5, kt = f % 5;
    int m = 16 * mt + (lane & 15);
    int k = 32 * kt + 8 * (lane >> 4) + j;
    int ci = (k < 80) ? k : k - 80;
    int kk = (k < 80) ? (255 - u) : (511 - u);
    condA[idx] = f2bf(mel_w[((size_t)m * 80 + ci) * 512 + kk]);
  }
  for (int idx = tid; idx < NBLK * 128; idx += stride)
    zb[idx] = dil_b[idx] + cond_b[idx];
  for (int idx = tid; idx < 128; idx += stride) {
    float s = 0.f;
    for (int i2 = 0; i2 < NBLK; ++i2) s += skip_b[i2 * 128 + idx];
    sbs[idx] = s;
  }
}

// ---- mel upsample MFMA; writes cond t-major [b][TP][96] bf16 ----
#define BSTR 168
__global__ __launch_bounds__(256) void cond_mfma(
    const float* __restrict__ mels, const ushort* __restrict__ condA,
    const float* __restrict__ mel_b, ushort* __restrict__ condb) {
  __shared__ ushort BT[128 * BSTR];
  const int tid = threadIdx.x;
  const int lane = tid & 63;
  const int w = tid >> 6;
  const int b = blockIdx.y;
  const int half = blockIdx.z;
  const int u = blockIdx.x * 4 + w;
  const int q4 = 4 * (lane >> 4);
  const int l15 = lane & 15;
  const float* melb = mels + (size_t)b * NMEL * FRAMES;
  for (int idx = tid; idx < 160 * 128; idx += 256) {
    int M = idx & 127;
    int k = idx >> 7;
    int ci = (k < 80) ? k : k - 80;
    int Mp = M + ((k < 80) ? 0 : 1);
    float v = (Mp < 128) ? melb[(size_t)ci * FRAMES + Mp] : 0.f;
    BT[M * BSTR + k] = f2bf(v);
  }
  __syncthreads();
  facc acc[5][4];
  #pragma unroll
  for (int mt = 0; mt < 5; ++mt) {
    #pragma unroll
    for (int nt = 0; nt < 4; ++nt) {
      #pragma unroll
      for (int r = 0; r < 4; ++r) acc[mt][nt][r] = mel_b[16 * mt + q4 + r];
    }
  }
  const ushort* cA = condA + (size_t)u * 25 * 512 + lane * 8;
  const int bofs = l15 * BSTR + 8 * (lane >> 4);
  #pragma unroll
  for (int kt = 0; kt < 5; ++kt) {
    bfrag a[5];
    #pragma unroll
    for (int mt = 0; mt < 5; ++mt) a[mt] = ldfrag(cA + (mt * 5 + kt) * 512);
    #pragma unroll
    for (int nt = 0; nt < 4; ++nt) {
      bfrag bb = ldfrag(&BT[(half * 64 + nt * 16) * BSTR + bofs + kt * 32]);
      #pragma unroll
      for (int mt = 0; mt < 5; ++mt) acc[mt][nt] = MFMA16(a[mt], bb, acc[mt][nt]);
    }
  }
  ushort* cbp = condb + (size_t)b * TP * 96;
  #pragma unroll
  for (int mt = 0; mt < 5; ++mt) {
    #pragma unroll
    for (int nt = 0; nt < 4; ++nt) {
      const int M = half * 64 + nt * 16 + l15;
      if (M < 127) {
        us4v p;
        #pragma unroll
        for (int r = 0; r < 4; ++r) p[r] = f2bf(acc[mt][nt][r]);
        const int t = M * 256 + u;
        *reinterpret_cast<us4v*>(&cbp[(size_t)(t + PAD) * 96 + 16 * mt + q4]) = p;
      }
    }
  }
}

// ---- init: res_0 fp32 + bf16, t-major rows [PAD, PAD+T) ----
__global__ __launch_bounds__(256) void init_res_kernel(
    const float* __restrict__ x, const float* __restrict__ iw,
    const float* __restrict__ ib, float* __restrict__ resf0,
    ushort* __restrict__ resh0) {
  int idx = blockIdx.x * blockDim.x + threadIdx.x;
  if (idx >= BATCH * T_LEN * 64) return;
  int c = idx & 63;
  int t = (idx >> 6) % T_LEN;
  int b = idx / (64 * T_LEN);
  float v = x[(size_t)b * T_LEN + t] * iw[c] + ib[c];
  size_t o = (size_t)b * TP * 64 + (size_t)(t + PAD) * 64 + c;
  resf0[o] = v;
  resh0[o] = f2bf(v);
}

// ============ pair kernel: layers (i0,i0+1), global bf16 B-fragments ============
template <int DEFER>
__global__ __launch_bounds__(256, 4) void wn_pair_kernel(
    const float* __restrict__ resf_in, float* __restrict__ resf_out,
    const ushort* __restrict__ resh_in, ushort* __restrict__ resh_out,
    const ushort* __restrict__ condb, const ushort* __restrict__ wa,
    const ushort* __restrict__ wsf, const ushort* __restrict__ wrf,
    const float* __restrict__ zb, const float* __restrict__ res_b,
    const float* __restrict__ skip_b, float* __restrict__ skipg,
    ushort* __restrict__ hb0, ushort* __restrict__ hb1, int i0, int d0,
    int writeRes) {
  __shared__ ushort HT[64 * 72];
  __shared__ ushort RTs[64 * 72];
  __shared__ ushort RTh[64 * 72];
  const int i1 = i0 + 1;
  const int d1 = 2 * d0;
  const int tid = threadIdx.x;
  const int lane = tid & 63;
  const int w = tid >> 6;
  const int l15 = lane & 15;
  const int q4 = 4 * (lane >> 4);
  const int colq = 8 * (lane >> 4);
  // bijective XCD swizzle (508 = 8*63+4)
  const int orig = blockIdx.x;
  const int xcd = orig & 7;
  const int loc = orig >> 3;
  const int tile = (xcd < 4 ? xcd * 64 : 256 + (xcd - 4) * 63) + loc;
  const int t0 = tile * 64;
  const int t0s = t0 - d1;
  const int b = blockIdx.y;

  const float* rfi = resf_in + (size_t)b * TP * 64;
  float* rfo = resf_out + (size_t)b * TP * 64;
  const ushort* rhi = resh_in + (size_t)b * TP * 64;
  ushort* rho = resh_out + (size_t)b * TP * 64;
  const ushort* cbp = condb + (size_t)b * TP * 96;
  const int bofs_h = l15 * 72 + colq;

  facc rs_s[4], rs_h[4], sk[8];
  facc accF[4], accG[4];
  if constexpr (!DEFER) {
    #pragma unroll
    for (int j = 0; j < 8; ++j) {
      const int ch = 32 * w + 16 * (j >> 2) + q4;
      facc s0 = *(const facc*)(skip_b + i0 * 128 + ch);
      facc s1 = *(const facc*)(skip_b + i1 * 128 + ch);
      sk[j] = s0 + s1;
    }
  }

#define ZG_INITB(LAYER)                                                       \
  _Pragma("unroll")                                                           \
  for (int nt = 0; nt < 4; ++nt) {                                            \
    accF[nt] = *(const facc*)(zb + (LAYER) * 128 + 16 * w + q4);              \
    accG[nt] = *(const facc*)(zb + (LAYER) * 128 + 64 + 16 * w + q4);         \
  }

#define ZG_GLOBAL(LAYER, TB)                                                  \
  {                                                                           \
    ZG_INITB(LAYER)                                                           \
    const ushort* wal = wa + (size_t)(LAYER) * 56 * 512 + lane * 8;           \
    const ushort* bp0[4];                                                     \
    const ushort* bp1[4];                                                     \
    const ushort* bpc[4];                                                     \
    _Pragma("unroll")                                                         \
    for (int nt = 0; nt < 4; ++nt) {                                          \
      const int tg = (TB) + nt * 16 + l15;                                    \
      bp0[nt] = rhi + (size_t)(tg - d0 + PAD) * 64 + colq;                    \
      bp1[nt] = rhi + (size_t)(tg + PAD) * 64 + colq;                         \
      bpc[nt] = cbp + (size_t)(tg + PAD) * 96 + colq;                         \
    }                                                                         \
    _Pragma("unroll")                                                         \
    for (int kt = 0; kt < 7; ++kt) {                                          \
      bfrag aF = ldfrag(wal + (w * 7 + kt) * 512);                            \
      bfrag aG = ldfrag(wal + ((w + 4) * 7 + kt) * 512);                      \
      _Pragma("unroll")                                                       \
      for (int nt = 0; nt < 4; ++nt) {                                        \
        bfrag bb = (kt < 2)   ? ldfrag(bp0[nt] + kt * 32)                     \
                   : (kt < 4) ? ldfrag(bp1[nt] + (kt - 2) * 32)               \
                              : ldfrag(bpc[nt] + (kt - 4) * 32);              \
        accF[nt] = MFMA16(aF, bb, accF[nt]);                                  \
        accG[nt] = MFMA16(aG, bb, accG[nt]);                                  \
      }                                                                       \
    }                                                                         \
  }

#define ZG_LDS(LAYER)                                                        \
  {                                                                           \
    ZG_INITB(LAYER)                                                           \
    const ushort* wal = wa + (size_t)(LAYER) * 56 * 512 + lane * 8;           \
    const ushort* bpc[4];                                                     \
    _Pragma("unroll")                                                         \
    for (int nt = 0; nt < 4; ++nt)                                            \
      bpc[nt] = cbp + (size_t)(t0 + nt * 16 + l15 + PAD) * 96 + colq;         \
    _Pragma("unroll")                                                         \
    for (int kt = 0; kt < 7; ++kt) {                                          \
      bfrag aF = ldfrag(wal + (w * 7 + kt) * 512);                            \
      bfrag aG = ldfrag(wal + ((w + 4) * 7 + kt) * 512);                      \
      _Pragma("unroll")                                                       \
      for (int nt = 0; nt < 4; ++nt) {                                        \
        bfrag bb = (kt < 2)                                                   \
            ? ldfrag(&RTs[(nt * 16 + l15) * 72 + kt * 32 + colq])             \
            : (kt < 4)                                                        \
                ? ldfrag(&RTh[(nt * 16 + l15) * 72 + (kt - 2) * 32 + colq])   \
                : ldfrag(bpc[nt] + (kt - 4) * 32);                            \
        accF[nt] = MFMA16(aF, bb, accF[nt]);                                  \
        accG[nt] = MFMA16(aG, bb, accG[nt]);                                  \
      }                                                                       \
    }                                                                         \
  }

#define GATE(HBPTR, DOHB)                                                     \
  {                                                                           \
    _Pragma("unroll")                                                         \
    for (int nt = 0; nt < 4; ++nt) {                                          \
      us4v p;                                                                 \
      _Pragma("unroll")                                                       \
      for (int r = 0; r < 4; ++r)                                             \
        p[r] = f2bf(tanhf_(accF[nt][r]) * sigmoidf_(accG[nt][r]));            \
      *reinterpret_cast<us4v*>(&HT[(nt * 16 + l15) * 72 + 16 * w + q4]) = p;  \
      if (DOHB)                                                               \
        *reinterpret_cast<us4v*>((HBPTR) + (size_t)b * T_LEN * 64 +           \
                                 (size_t)(t0 + nt * 16 + l15) * 64 +          \
                                 16 * w + q4) = p;                            \
    }                                                                         \
  }

#define RES_GEMM(LAYER, RS)                                                   \
  {                                                                           \
    const ushort* wrl = wrf + (size_t)(LAYER) * 8 * 512 + lane * 8;           \
    _Pragma("unroll")                                                         \
    for (int kt = 0; kt < 2; ++kt) {                                          \
      bfrag ar = ldfrag(wrl + (w * 2 + kt) * 512);                            \
      _Pragma("unroll")                                                       \
      for (int nt = 0; nt < 4; ++nt) {                                        \
        bfrag bb = ldfrag(&HT[nt * 16 * 72 + bofs_h + kt * 32]);              \
        RS[nt] = MFMA16(ar, bb, RS[nt]);                                      \
      }                                                                       \
    }                                                                         \
  }

#define SKIP_GEMM(LAYER)                                                      \
  {                                                                           \
    const ushort* wsl = wsf + (size_t)(LAYER) * 16 * 512 + lane * 8;          \
    _Pragma("unroll")                                                         \
    for (int kt = 0; kt < 2; ++kt) {                                          \
      bfrag a0 = ldfrag(wsl + ((2 * w) * 2 + kt) * 512);                      \
      bfrag a1 = ldfrag(wsl + ((2 * w + 1) * 2 + kt) * 512);                  \
      _Pragma("unroll")                                                       \
      for (int nt = 0; nt < 4; ++nt) {                                        \
        bfrag bb = ldfrag(&HT[nt * 16 * 72 + bofs_h + kt * 32]);              \
        sk[nt] = MFMA16(a0, bb, sk[nt]);                                      \
        sk[4 + nt] = MFMA16(a1, bb, sk[4 + nt]);                              \
      }                                                                       \
    }                                                                         \
  }

  // ===== ctx S: layer i0 @ shifted tile =====
  ZG_GLOBAL(i0, t0s);
  GATE(hb0, 0);
  __syncthreads();
  // rs_s base from bf16 mirror (shifted ctx feeds only bf16 taps downstream)
  #pragma unroll
  for (int nt = 0; nt < 4; ++nt) {
    const int tg = t0s + nt * 16 + l15;
    us4v hv = *(const us4v*)(rhi + (size_t)(tg + PAD) * 64 + 16 * w + q4);
    facc rbv = *(const facc*)(res_b + i0 * 64 + 16 * w + q4);
    #pragma unroll
    for (int r = 0; r < 4; ++r) rs_s[nt][r] = bf2f(hv[r]) + rbv[r];
  }
  RES_GEMM(i0, rs_s);
  #pragma unroll
  for (int nt = 0; nt < 4; ++nt) {
    const bool ok = (t0s + nt * 16 + l15) >= 0;
    us4v p;
    #pragma unroll
    for (int r = 0; r < 4; ++r) p[r] = ok ? f2bf(rs_s[nt][r]) : (ushort)0;
    *reinterpret_cast<us4v*>(&RTs[(nt * 16 + l15) * 72 + 16 * w + q4]) = p;
  }
  __syncthreads();
  // ===== ctx H: layer i0 @ home =====
  ZG_GLOBAL(i0, t0);
  GATE(hb0, DEFER);
  __syncthreads();
  #pragma unroll
  for (int nt = 0; nt < 4; ++nt) {
    const int tg = t0 + nt * 16 + l15;
    facc v = *(const facc*)(rfi + (size_t)(tg + PAD) * 64 + 16 * w + q4);
    facc rbv = *(const facc*)(res_b + i0 * 64 + 16 * w + q4);
    rs_h[nt] = v + rbv;
  }
  if constexpr (!DEFER) { SKIP_GEMM(i0); }
  RES_GEMM(i0, rs_h);
  #pragma unroll
  for (int nt = 0; nt < 4; ++nt) {
    us4v p;
    #pragma unroll
    for (int r = 0; r < 4; ++r) p[r] = f2bf(rs_h[nt][r]);
    *reinterpret_cast<us4v*>(&RTh[(nt * 16 + l15) * 72 + 16 * w + q4]) = p;
  }
  __syncthreads();
  // ===== layer i1 @ home (taps from RTs/RTh) =====
  ZG_LDS(i1);
  GATE(hb1, DEFER);
  __syncthreads();
  #pragma unroll
  for (int nt = 0; nt < 4; ++nt) {
    facc rbv = *(const facc*)(res_b + i1 * 64 + 16 * w + q4);
    rs_s[nt] = rs_h[nt] + rbv;
  }
  if constexpr (!DEFER) { SKIP_GEMM(i1); }
  RES_GEMM(i1, rs_s);
  // ===== epilogue =====
  if (writeRes) {
    #pragma unroll
    for (int nt = 0; nt < 4; ++nt) {
      const int tg = t0 + nt * 16 + l15;
      *(facc*)(rfo + (size_t)(tg + PAD) * 64 + 16 * w + q4) = rs_s[nt];
      us4v p;
      #pragma unroll
      for (int r = 0; r < 4; ++r) p[r] = f2bf(rs_s[nt][r]);
      *reinterpret_cast<us4v*>(rho + (size_t)(tg + PAD) * 64 + 16 * w + q4) = p;
    }
  }
  if constexpr (!DEFER) {
    float* sg = skipg + (size_t)b * T_LEN * 128;
    #pragma unroll
    for (int nt = 0; nt < 4; ++nt) {
      const int tg = t0 + nt * 16 + l15;
      facc* p0 = (facc*)(sg + (size_t)tg * 128 + 32 * w + q4);
      facc* p1 = (facc*)(sg + (size_t)tg * 128 + 32 * w + 16 + q4);
      *p0 = *p0 + sk[nt];
      *p1 = *p1 + sk[4 + nt];
    }
  }
#undef ZG_INITB
#undef ZG_GLOBAL
#undef ZG_LDS
#undef GATE
#undef RES_GEMM
#undef SKIP_GEMM
}

// ---- skip_accum v3: LDS-staged h, 32-t blocks; optional fused post1 ----
// FIRST: no skipg read (init 0).  FUSE: no skipg write; fused post1 -> y1r.
template <int FIRST, int FUSE>
__global__ __launch_bounds__(256) void skip_accum(
    const ushort* __restrict__ hb, const ushort* __restrict__ wsf,
    float* __restrict__ skipg, const float* __restrict__ sbs,
    const ushort* __restrict__ wp1, const float* __restrict__ p1b,
    ushort* __restrict__ y1r, int base, int nl) {
  __shared__ ushort HL[12 * 2048];  // 12 layer-tiles x 4KB (linear for gload_lds)
  const int tid = threadIdx.x;
  const int lane = tid & 63;
  const int w = tid >> 6;
  const int l15 = lane & 15;
  const int q4 = 4 * (lane >> 4);
  const int colq = 8 * (lane >> 4);
  const int t0 = blockIdx.x * 32;
  const int b = blockIdx.y;

  // stage nl h-tiles (contiguous 4KB each) with inverse-swizzled source
  {
    const int D = tid * 16;                     // dest byte within tile
    const int Dsw = D ^ (((D >> 7) & 7) << 4);  // involution on bits 4-6
    const char* srcb =
        (const char*)(hb + (size_t)b * T_LEN * 64 + (size_t)t0 * 64);
    char* ldsb = (char*)HL + (tid >> 6) * 1024;  // wave-uniform base
    for (int l = 0; l < nl; ++l)
      gload_lds16(srcb + (size_t)l * SLOT_BYTES + Dsw, ldsb + l * 4096);
  }

  float* sg = skipg + (size_t)b * T_LEN * 128;
  facc a0[2], a1[2];
  if constexpr (FIRST) {
    #pragma unroll
    for (int nt = 0; nt < 2; ++nt) {
      #pragma unroll
      for (int r = 0; r < 4; ++r) { a0[nt][r] = 0.f; a1[nt][r] = 0.f; }
    }
  } else {
    #pragma unroll
    for (int nt = 0; nt < 2; ++nt) {
      const int tg = t0 + nt * 16 + l15;
      a0[nt] = *(const facc*)(sg + (size_t)tg * 128 + 32 * w + q4);
      a1[nt] = *(const facc*)(sg + (size_t)tg * 128 + 32 * w + 16 + q4);
    }
  }
  __syncthreads();  // staging complete (vmcnt drained by barrier semantics)

  for (int l = 0; l < nl; ++l) {
    const ushort* wsl = wsf + (size_t)(base + l) * 16 * 512 + lane * 8;
    #pragma unroll
    for (int kt = 0; kt < 2; ++kt) {
      bfrag f0 = ldfrag(wsl + ((2 * w) * 2 + kt) * 512);
      bfrag f1 = ldfrag(wsl + ((2 * w + 1) * 2 + kt) * 512);
      #pragma unroll
      for (int nt = 0; nt < 2; ++nt) {
        const int t = nt * 16 + l15;
        int byteoff = t * 128 + kt * 64 + colq * 2;
        byteoff ^= ((t & 7) << 4);
        bfrag bb = ldfrag((const ushort*)((const char*)HL + l * 4096 + byteoff));
        a0[nt] = MFMA16(f0, bb, a0[nt]);
        a1[nt] = MFMA16(f1, bb, a1[nt]);
      }
    }
  }

  if constexpr (!FUSE) {
    #pragma unroll
    for (int nt = 0; nt < 2; ++nt) {
      const int tg = t0 + nt * 16 + l15;
      *(facc*)(sg + (size_t)tg * 128 + 32 * w + q4) = a0[nt];
      *(facc*)(sg + (size_t)tg * 128 + 32 * w + 16 + q4) = a1[nt];
    }
  } else {
    // fused post1: ST = bf16(relu(skip + sbs)); y1 = bf16(relu(P1@ST + b))
    __syncthreads();
    ushort* ST = HL;  // [32][136]
    #pragma unroll
    for (int nt = 0; nt < 2; ++nt) {
      us4v p0, p1;
      #pragma unroll
      for (int r = 0; r < 4; ++r) {
        p0[r] = f2bf(fmaxf(a0[nt][r] + sbs[32 * w + q4 + r], 0.f));
        p1[r] = f2bf(fmaxf(a1[nt][r] + sbs[32 * w + 16 + q4 + r], 0.f));
      }
      const int row = nt * 16 + l15;
      *reinterpret_cast<us4v*>(&ST[row * 136 + 32 * w + q4]) = p0;
      *reinterpret_cast<us4v*>(&ST[row * 136 + 32 * w + 16 + q4]) = p1;
    }
    __syncthreads();
    facc acc2[4][2];
    #pragma unroll
    for (int mi = 0; mi < 4; ++mi) {
      #pragma unroll
      for (int nt = 0; nt < 2; ++nt) {
        #pragma unroll
        for (int r = 0; r < 4; ++r)
          acc2[mi][nt][r] = p1b[16 * (4 * w + mi) + q4 + r];
      }
    }
    const int lo = lane * 8;
    #pragma unroll
    for (int kt = 0; kt < 4; ++kt) {
      bfrag am[4];
      #pragma unroll
      for (int mi = 0; mi < 4; ++mi)
        am[mi] = ldfrag(wp1 + ((4 * w + mi) * 4 + kt) * 512 + lo);
      #pragma unroll
      for (int nt = 0; nt < 2; ++nt) {
        bfrag bb = ldfrag(&ST[(nt * 16 + l15) * 136 + kt * 32 + colq]);
        #pragma unroll
        for (int mi = 0; mi < 4; ++mi)
          acc2[mi][nt] = MFMA16(am[mi], bb, acc2[mi][nt]);
      }
    }
    ushort* yb = y1r + (size_t)b * 256 * T_LEN;
    #pragma unroll
    for (int mi = 0; mi < 4; ++mi) {
      #pragma unroll
      for (int nt = 0; nt < 2; ++nt) {
        const int tt = t0 + nt * 16 + l15;
        #pragma unroll
        for (int r = 0; r < 4; ++r)
          yb[(size_t)(16 * (4 * w + mi) + q4 + r) * T_LEN + tt] =
              f2bf(fmaxf(acc2[mi][nt][r], 0.f));
      }
    }
  }
}

// ---- standalone post1 (non-defer fallback only; sbs may be null) ----
#define FSSTR 136
__global__ __launch_bounds__(256) void post1_mfma(
    const float* __restrict__ skipg, const float* __restrict__ sbs,
    const ushort* __restrict__ wp1, const float* __restrict__ p1b,
    ushort* __restrict__ y1r) {
  __shared__ ushort ST[64 * FSSTR];
  const int tid = threadIdx.x;
  const int lane = tid & 63;
  const int w = tid >> 6;
  const int t0 = blockIdx.x * 64;
  const int b = blockIdx.y;
  {
    const int t = tid & 63;
    const int kc = tid >> 6;
    const float* sp =
        skipg + (size_t)b * T_LEN * 128 + (size_t)(t0 + t) * 128 + kc * 32;
    #pragma unroll
    for (int j = 0; j < 8; ++j) {
      facc v = *(const facc*)(sp + j * 4);
      us4v o;
      #pragma unroll
      for (int r = 0; r < 4; ++r) {
        float s = sbs ? sbs[kc * 32 + j * 4 + r] : 0.f;
        o[r] = f2bf(fmaxf(v[r] + s, 0.f));
      }
      *reinterpret_cast<us4v*>(&ST[t * FSSTR + kc * 32 + j * 4]) = o;
    }
  }
  __syncthreads();
  const int q4 = 4 * (lane >> 4);
  facc acc[4][4];
  #pragma unroll
  for (int mi = 0; mi < 4; ++mi) {
    #pragma unroll
    for (int nt = 0; nt < 4; ++nt) {
      #pragma unroll
      for (int r = 0; r < 4; ++r)
        acc[mi][nt][r] = p1b[16 * (4 * w + mi) + q4 + r];
    }
  }
  const int lo = lane * 8;
  const int bofs = (lane & 15) * FSSTR + 8 * (lane >> 4);
  #pragma unroll
  for (int kt = 0; kt < 4; ++kt) {
    bfrag a[4];
    #pragma unroll
    for (int mi = 0; mi < 4; ++mi)
      a[mi] = ldfrag(wp1 + ((4 * w + mi) * 4 + kt) * 512 + lo);
    #pragma unroll
    for (int nt = 0; nt < 4; ++nt) {
      bfrag bb = ldfrag(&ST[nt * 16 * FSSTR + bofs + kt * 32]);
      #pragma unroll
      for (int mi = 0; mi < 4; ++mi) acc[mi][nt] = MFMA16(a[mi], bb, acc[mi][nt]);
    }
  }
  ushort* yb = y1r + (size_t)b * 256 * T_LEN;
  #pragma unroll
  for (int mi = 0; mi < 4; ++mi) {
    #pragma unroll
    for (int nt = 0; nt < 4; ++nt) {
      const int tt = t0 + nt * 16 + (lane & 15);
      #pragma unroll
      for (int r = 0; r < 4; ++r)
        yb[(size_t)(16 * (4 * w + mi) + q4 + r) * T_LEN + tt] =
            f2bf(fmaxf(acc[mi][nt][r], 0.f));
    }
  }
}

// ---- post2: out = p2_w @ y1r + b (fp32) ----
#define YSTR 264
__global__ __launch_bounds__(256) void post2_mfma(
    const ushort* __restrict__ y1r, const ushort* __restrict__ wp2,
    const float* __restrict__ p2b, float* __restrict__ out) {
  __shared__ ushort YT[64 * YSTR];
  const int tid = threadIdx.x;
  const int lane = tid & 63;
  const int w = tid >> 6;
  const int t0 = blockIdx.x * 64;
  const int b = blockIdx.y;
  const ushort* yb = y1r + (size_t)b * 256 * T_LEN;
  const int t = t0 + lane;
  for (int kc = 0; kc < 8; ++kc) {
    int k0 = w * 64 + kc * 8;
    us8v v;
    #pragma unroll
    for (int j = 0; j < 8; ++j) v[j] = yb[(size_t)(k0 + j) * T_LEN + t];
    *reinterpret_cast<us8v*>(&YT[lane * YSTR + k0]) = v;
  }
  __syncthreads();
  const int q4 = 4 * (lane >> 4);
  facc acc[4][4];
  #pragma unroll
  for (int mi = 0; mi < 4; ++mi) {
    #pragma unroll
    for (int nt = 0; nt < 4; ++nt) {
      #pragma unroll
      for (int r = 0; r < 4; ++r)
        acc[mi][nt][r] = p2b[16 * (4 * w + mi) + q4 + r];
    }
  }
  const int lo = lane * 8;
  const int bofs = (lane & 15) * YSTR + 8 * (lane >> 4);
  #pragma unroll
  for (int kt = 0; kt < 8; ++kt) {
    bfrag a[4];
    #pragma unroll
    for (int mi = 0; mi < 4; ++mi)
      a[mi] = ldfrag(wp2 + ((4 * w + mi) * 8 + kt) * 512 + lo);
    #pragma unroll
    for (int nt = 0; nt < 4; ++nt) {
      bfrag bb = ldfrag(&YT[nt * 16 * YSTR + bofs + kt * 32]);
      #pragma unroll
      for (int mi = 0; mi < 4; ++mi) acc[mi][nt] = MFMA16(a[mi], bb, acc[mi][nt]);
    }
  }
  float* ob = out + (size_t)b * 256 * T_LEN;
  #pragma unroll
  for (int mi = 0; mi < 4; ++mi) {
    #pragma unroll
    for (int nt = 0; nt < 4; ++nt) {
      const int tt = t0 + nt * 16 + (lane & 15);
      #pragma unroll
      for (int r = 0; r < 4; ++r)
        ob[(size_t)(16 * (4 * w + mi) + q4 + r) * T_LEN + tt] = acc[mi][nt][r];
    }
  }
}

extern "C" void kernel_launch(void* const* d_in, const int* in_sizes, int n_in,
                              void* d_out, int out_size, void* d_ws,
                              size_t ws_size, hipStream_t stream) {
  const float* x       = (const float*)d_in[0];
  const float* mels    = (const float*)d_in[1];
  const float* input_w = (const float*)d_in[2];
  const float* input_b = (const float*)d_in[3];
  const float* mel_w   = (const float*)d_in[4];
  const float* mel_b   = (const float*)d_in[5];
  const float* dil_w   = (const float*)d_in[6];
  const float* dil_b   = (const float*)d_in[7];
  const float* cond_w  = (const float*)d_in[8];
  const float* cond_b  = (const float*)d_in[9];
  const float* skip_w  = (const float*)d_in[10];
  const float* skip_b  = (const float*)d_in[11];
  const float* res_w   = (const float*)d_in[12];
  const float* res_b   = (const float*)d_in[13];
  const float* p1_w    = (const float*)d_in[14];
  const float* p1_b    = (const float*)d_in[15];
  const float* p2_w    = (const float*)d_in[16];
  const float* p2_b    = (const float*)d_in[17];

  char* ws = (char*)d_ws;
  float* rfA    = (float*)(ws + RESF_OFF);
  float* rfB    = rfA + (size_t)2 * TP * 64;
  ushort* rhA   = (ushort*)(ws + RESH_OFF);
  ushort* rhB   = rhA + (size_t)2 * TP * 64;
  ushort* condb = (ushort*)(ws + CONDB_OFF);
  ushort* wa    = (ushort*)(ws + WA_OFF);
  ushort* wsf   = (ushort*)(ws + WSF_OFF);
  ushort* wrf   = (ushort*)(ws + WRF_OFF);
  ushort* wp1   = (ushort*)(ws + WP1_OFF);
  ushort* wp2   = (ushort*)(ws + WP2_OFF);
  float* zbp    = (float*)(ws + ZB_OFF);
  float* sbsp   = (float*)(ws + SBS_OFF);
  float* skipg  = (float*)(ws + SKIPG_OFF);
  ushort* condA = (ushort*)(ws + CONDA_OFF);
  ushort* hbuf  = (ushort*)(ws + HB_OFF);
  ushort* y1rp  = (ushort*)(ws + Y1R_OFF);
  float* out    = (float*)d_out;

  // group size G (pairs per h-deferral group); cap 6 (12 LDS-staged layers)
  int G = 0;
  if (ws_size >= (size_t)HB_OFF + 12ull * SLOT_BYTES) {
    G = 6;
  } else if (ws_size >= (size_t)HB_OFF + 2ull * SLOT_BYTES) {
    G = (int)((ws_size - HB_OFF) / (2ull * SLOT_BYTES));
    if (G > 6) G = 6;
  }
  const bool defer = (G >= 1);

  // zero prefixes (causal padding) + cond buffer pads
  for (int k = 0; k < 2; ++k)
    for (int b = 0; b < 2; ++b) {
      hipMemsetAsync((char*)(k == 0 ? rfA : rfB) + (size_t)b * TP * 64 * 4, 0,
                     (size_t)PAD * 64 * 4, stream);
      hipMemsetAsync((char*)(k == 0 ? rhA : rhB) + (size_t)b * TP * 64 * 2, 0,
                     (size_t)PAD * 64 * 2, stream);
    }
  hipMemsetAsync(condb, 0, (size_t)2 * TP * 96 * 2, stream);

  prep_kernel<<<2048, 256, 0, stream>>>(dil_w, cond_w, skip_w, res_w, p1_w,
                                        p2_w, mel_w, dil_b, cond_b, skip_b, wa,
                                        wsf, wrf, wp1, wp2, condA, zbp, sbsp);
  cond_mfma<<<dim3(64, BATCH, 2), 256, 0, stream>>>(mels, condA, mel_b, condb);
  if (!defer) {
    // non-defer path accumulates into skipg in-kernel -> needs zeros
    hipMemsetAsync(skipg, 0, (size_t)2 * T_LEN * 128 * 4, stream);
  }
  init_res_kernel<<<(BATCH * T_LEN * 64 + 255) / 256, 256, 0, stream>>>(
      x, input_w, input_b, rfA, rhA);

  float* rfi = rfA;
  float* rfo = rfB;
  ushort* rhi = rhA;
  ushort* rho = rhB;
  int groupStart = 0;
  const dim3 ag(T_LEN / 32, BATCH);
  for (int p = 0; p < NPAIRS; ++p) {
    int i0 = 2 * p;
    int d0 = 1 << (i0 % 10);
    int wr = (p < NPAIRS - 1) ? 1 : 0;
    if (defer) {
      ushort* h0 = hbuf + (size_t)(2 * (p - groupStart)) * SLOT_ELEMS;
      wn_pair_kernel<1><<<dim3(NTILES, BATCH), 256, 0, stream>>>(
          rfi, rfo, rhi, rho, condb, wa, wsf, wrf, zbp, res_b, skip_b, skipg,
          h0, h0 + SLOT_ELEMS, i0, d0, wr);
      if (p - groupStart + 1 == G || p == NPAIRS - 1) {
        int nl = 2 * (p - groupStart + 1);
        int base = 2 * groupStart;
        bool isF = (groupStart == 0);
        bool isL = (p == NPAIRS - 1);
        if (isF && isL)
          skip_accum<1, 1><<<ag, 256, 0, stream>>>(hbuf, wsf, skipg, sbsp, wp1,
                                                   p1_b, y1rp, base, nl);
        else if (isF)
          skip_accum<1, 0><<<ag, 256, 0, stream>>>(hbuf, wsf, skipg, sbsp, wp1,
                                                   p1_b, y1rp, base, nl);
        else if (isL)
          skip_accum<0, 1><<<ag, 256, 0, stream>>>(hbuf, wsf, skipg, sbsp, wp1,
                                                   p1_b, y1rp, base, nl);
        else
          skip_accum<0, 0><<<ag, 256, 0, stream>>>(hbuf, wsf, skipg, sbsp, wp1,
                                                   p1_b, y1rp, base, nl);
        groupStart = p + 1;
      }
    } else {
      wn_pair_kernel<0><<<dim3(NTILES, BATCH), 256, 0, stream>>>(
          rfi, rfo, rhi, rho, condb, wa, wsf, wrf, zbp, res_b, skip_b, skipg,
          nullptr, nullptr, i0, d0, wr);
    }
    float* tf = rfi; rfi = rfo; rfo = tf;
    ushort* th = rhi; rhi = rho; rho = th;
  }

  if (!defer) {
    post1_mfma<<<dim3(NTILES, BATCH), 256, 0, stream>>>(skipg, nullptr, wp1,
                                                        p1_b, y1rp);
  }
  post2_mfma<<<dim3(NTILES, BATCH), 256, 0, stream>>>(y1rp, wp2, p2_b, out);
}